// Round 14
// baseline (1728.162 us; speedup 1.0000x reference)
//
#include <hip/hip_runtime.h>
#include <hip/hip_bf16.h>

// ---------------------------------------------------------------------------
// TrainableVarRegBlock: 2-level demons registration (48^3, 96^3), 2 iters each.
// conv1/2/3/4 via bf16 MFMA 16x16x32 (R11-proven structure). Activations
// voxel-major [vox][ci] bf16, stored RAW; InstanceNorm+Mish applied in the
// CONSUMER conv's LDS staging (removes 12 inorm dispatches). warp+forces
// fused into one kernel (LDS warped tile). Fragment-ordered B weights,
// fused IN stage-1, R5 swizzle, fast rational Mish. Force path f32.
// ---------------------------------------------------------------------------

#define DEV __device__ __forceinline__
typedef __hip_bfloat16 bf16;
typedef __attribute__((ext_vector_type(8))) short short8;
typedef __attribute__((ext_vector_type(4))) float f32x4;

DEV float bfu(unsigned int u) {           // bf16 bits -> f32 (exact)
  union { unsigned int i; float f; } x; x.i = u << 16; return x.f;
}
DEV unsigned short fbf(float f) {         // f32 -> bf16 bits (RNE)
  __hip_bfloat16 h = __float2bfloat16(f);
  return __builtin_bit_cast(unsigned short, h);
}

// fast mish: x*tanh(softplus(x)) == x*(u^2+2u)/(u^2+2u+2), u=e^x (exact algebra)
DEV float mishf(float v) {
  if (v > 20.f) return v;
  float u = __expf(v);
  float w = u * (u + 2.f);
  return v * (w / (w + 2.f));
}

// ---------------- small utility kernels ----------------
__global__ void zero_k(float* __restrict__ p, int n) {
  int i = blockIdx.x * 256 + threadIdx.x;
  if (i < n) p[i] = 0.f;
}
__global__ void copy_k(const float* __restrict__ in, float* __restrict__ out, int n) {
  int i = blockIdx.x * 256 + threadIdx.x;
  if (i < n) out[i] = in[i];
}

// 16x16 fragment pack: dst[((off*NWT+nwt)*KB+kb)*512 + lane*8 + j]
// = w[co = nwt*16 + (lane&15)][ci = (kb*4 + (lane>>4))*8 + j]  (zero-padded)
__global__ void pack_wf_k(const float* __restrict__ w, bf16* __restrict__ dst,
                          int NWT, int KB, int COR, int CIR) {
  int idx = blockIdx.x * 256 + threadIdx.x;
  int tot = 27 * NWT * KB * 512;
  if (idx >= tot) return;
  int j = idx & 7;
  int lane = (idx >> 3) & 63;
  int frag = idx >> 9;
  int kb = frag % KB;
  int r2 = frag / KB;
  int nwt = r2 % NWT;
  int off = r2 / NWT;
  int co = nwt * 16 + (lane & 15);
  int ci = (kb * 4 + (lane >> 4)) * 8 + j;
  float v = (co < COR && ci < CIR) ? w[((size_t)co * CIR + ci) * 27 + off] : 0.f;
  dst[idx] = __float2bfloat16(v);
}

// ---------------- resize helpers ----------------
DEV int ds_taps(int i, int n_out, int* j0, float* w) {
  if (i == 0) { *j0 = 0; w[0] = 3.f/7.f; w[1] = 3.f/7.f; w[2] = 1.f/7.f; return 3; }
  if (i == n_out - 1) { *j0 = 2*i - 1; w[0] = 1.f/7.f; w[1] = 3.f/7.f; w[2] = 3.f/7.f; return 3; }
  *j0 = 2*i - 1; w[0] = 0.125f; w[1] = 0.375f; w[2] = 0.375f; w[3] = 0.125f; return 4;
}
DEV void up_taps(int i, int n_in, int* j0, int* j1, float* w0, float* w1) {
  if (i & 1) {
    int k = i >> 1;
    if (k + 1 >= n_in) { *j0 = n_in - 1; *j1 = n_in - 1; *w0 = 1.f; *w1 = 0.f; }
    else { *j0 = k; *j1 = k + 1; *w0 = 0.75f; *w1 = 0.25f; }
  } else {
    int k = i >> 1;
    if (k == 0) { *j0 = 0; *j1 = 0; *w0 = 1.f; *w1 = 0.f; }
    else { *j0 = k - 1; *j1 = k; *w0 = 0.25f; *w1 = 0.75f; }
  }
}

__global__ void down2x_k(const float* __restrict__ in, float* __restrict__ out,
                         int Do, int Ho, int Wo) {
  const int Hi = 2 * Ho, Wi = 2 * Wo;
  const int No = Do * Ho * Wo;
  int i = blockIdx.x * 256 + threadIdx.x;
  if (i >= No) return;
  int xo = i % Wo; int t = i / Wo; int yo = t % Ho; int zo = t / Ho;
  int jz0, jy0, jx0; float wz[4], wy[4], wx[4];
  int cz = ds_taps(zo, Do, &jz0, wz);
  int cy = ds_taps(yo, Ho, &jy0, wy);
  int cx = ds_taps(xo, Wo, &jx0, wx);
  float s = 0.f;
  for (int a = 0; a < cz; ++a) {
    const float* pz = in + (size_t)(jz0 + a) * Hi * Wi;
    for (int b = 0; b < cy; ++b) {
      const float* py = pz + (size_t)(jy0 + b) * Wi;
      float wab = wz[a] * wy[b];
      for (int d = 0; d < cx; ++d) s += wab * wx[d] * py[jx0 + d];
    }
  }
  out[i] = s;
}

__global__ void up2x_vf_k(const float* __restrict__ in, float* __restrict__ out,
                          int Do, int Ho, int Wo) {
  const int Di = Do / 2, Hi = Ho / 2, Wi = Wo / 2;
  const int No = Do * Ho * Wo;
  const int c = blockIdx.y;
  int i = blockIdx.x * 256 + threadIdx.x;
  if (i >= No) return;
  int xo = i % Wo; int t = i / Wo; int yo = t % Ho; int zo = t / Ho;
  int jz0, jz1, jy0, jy1, jx0, jx1; float wz0, wz1, wy0, wy1, wx0, wx1;
  up_taps(zo, Di, &jz0, &jz1, &wz0, &wz1);
  up_taps(yo, Hi, &jy0, &jy1, &wy0, &wy1);
  up_taps(xo, Wi, &jx0, &jx1, &wx0, &wx1);
  const float* p = in + (size_t)c * Di * Hi * Wi;
  float v00 = wx0 * p[(jz0 * Hi + jy0) * Wi + jx0] + wx1 * p[(jz0 * Hi + jy0) * Wi + jx1];
  float v01 = wx0 * p[(jz0 * Hi + jy1) * Wi + jx0] + wx1 * p[(jz0 * Hi + jy1) * Wi + jx1];
  float v10 = wx0 * p[(jz1 * Hi + jy0) * Wi + jx0] + wx1 * p[(jz1 * Hi + jy0) * Wi + jx1];
  float v11 = wx0 * p[(jz1 * Hi + jy1) * Wi + jx0] + wx1 * p[(jz1 * Hi + jy1) * Wi + jx1];
  float s = wz0 * (wy0 * v00 + wy1 * v01) + wz1 * (wy0 * v10 + wy1 * v11);
  out[(size_t)c * No + i] = 2.f * s;
}

// ---------------- warp helper (trilinear, border clamp) ----------------------
DEV float warp1(const float* __restrict__ img, const float* __restrict__ vf,
                int x, int y, int z, size_t i, int D, int H, int W, size_t N) {
  float zc = fminf(fmaxf((float)z + vf[i], 0.f), (float)(D - 1));
  float yc = fminf(fmaxf((float)y + vf[N + i], 0.f), (float)(H - 1));
  float xc = fminf(fmaxf((float)x + vf[2 * N + i], 0.f), (float)(W - 1));
  float zf = floorf(zc), yf = floorf(yc), xf = floorf(xc);
  int z0 = (int)zf, y0 = (int)yf, x0 = (int)xf;
  float wz = zc - zf, wy = yc - yf, wx = xc - xf;
  int z1 = min(z0 + 1, D - 1), y1 = min(y0 + 1, H - 1), x1 = min(x0 + 1, W - 1);
  const int HW = H * W;
  float v000 = img[z0 * HW + y0 * W + x0];
  float v001 = img[z0 * HW + y0 * W + x1];
  float v010 = img[z0 * HW + y1 * W + x0];
  float v011 = img[z0 * HW + y1 * W + x1];
  float v100 = img[z1 * HW + y0 * W + x0];
  float v101 = img[z1 * HW + y0 * W + x1];
  float v110 = img[z1 * HW + y1 * W + x0];
  float v111 = img[z1 * HW + y1 * W + x1];
  return v000 * (1 - wz) * (1 - wy) * (1 - wx)
       + v001 * (1 - wz) * (1 - wy) * wx
       + v010 * (1 - wz) * wy * (1 - wx)
       + v011 * (1 - wz) * wy * wx
       + v100 * wz * (1 - wy) * (1 - wx)
       + v101 * wz * (1 - wy) * wx
       + v110 * wz * wy * (1 - wx)
       + v111 * wz * wy * wx;
}

__global__ void warp_k(const float* __restrict__ img, const float* __restrict__ vf,
                       float* __restrict__ out, int D, int H, int W) {
  const size_t N = (size_t)D * H * W;
  size_t i = (size_t)blockIdx.x * 256 + threadIdx.x;
  if (i >= N) return;
  int x = i % W; int t = i / W; int y = t % H; int z = t / H;
  out[i] = warp1(img, vf, x, y, z, i, D, H, W, N);
}

// ---------------- fused warp + demon forces -> feat [vox][8] bf16 ------------
// Block tile 8x8x4; LDS holds warped for 10x10x6 halo region.
__global__ void __launch_bounds__(256) warpforce_k(
    const float* __restrict__ img, const float* __restrict__ vf,
    const float* __restrict__ si, bf16* __restrict__ feat, int D, int H, int W) {
  __shared__ float wt[600];
  const size_t N = (size_t)D * H * W;
  const int t = threadIdx.x;
  const int tx = t & 7, ty = (t >> 3) & 7, tz = t >> 6;
  const int gx0 = blockIdx.x * 8, gy0 = blockIdx.y * 8, gz0 = blockIdx.z * 4;
  for (int cid = t; cid < 600; cid += 256) {
    int hx = cid % 10; int r = cid / 10; int hy = r % 10; int hz = r / 10;
    int gz = gz0 + hz - 1, gy = gy0 + hy - 1, gx = gx0 + hx - 1;
    float w = 0.f;
    if (((unsigned)gz < (unsigned)D) & ((unsigned)gy < (unsigned)H) & ((unsigned)gx < (unsigned)W)) {
      size_t i = (size_t)(gz * H + gy) * W + gx;
      w = warp1(img, vf, gx, gy, gz, i, D, H, W, N);
    }
    wt[cid] = w;
  }
  __syncthreads();
  const int x = gx0 + tx, y = gy0 + ty, z = gz0 + tz;
  const size_t i = (size_t)(z * H + y) * W + x;
  const int c = (tz + 1) * 100 + (ty + 1) * 10 + (tx + 1);
  float wv = wt[c];
  float gz = (z == 0) ? (wt[c + 100] - wv) : (z == D - 1) ? (wv - wt[c - 100]) : 0.5f * (wt[c + 100] - wt[c - 100]);
  float gy = (y == 0) ? (wt[c + 10] - wv) : (y == H - 1) ? (wv - wt[c - 10]) : 0.5f * (wt[c + 10] - wt[c - 10]);
  float gx = (x == 0) ? (wt[c + 1] - wv) : (x == W - 1) ? (wv - wt[c - 1]) : 0.5f * (wt[c + 1] - wt[c - 1]);
  float s = si[i];
  float diff = wv - s;
  float denom = gz * gz + gy * gy + gx * gx + diff * diff + 1e-9f;
  short8 o;
  o[0] = (short)fbf((diff * gz) / denom);
  o[1] = (short)fbf((diff * gy) / denom);
  o[2] = (short)fbf((diff * gx) / denom);
  o[3] = (short)fbf(s);
  o[4] = (short)fbf(wv);
  o[5] = 0; o[6] = 0; o[7] = 0;
  *(short8*)((short*)feat + i * 8) = o;
}

// ---------------- MFMA 3^3 conv: 27 shifted GEMMs (R11 structure) -----------
// act [vox][INS or CIN] bf16 (RAW conv output) -> out [vox][COUT] bf16 (RAW).
// NORM: apply InstanceNorm+Mish (musc) during LDS staging; OOB stages 0
// (zero-pad in normed domain). REDUCE: fused stage-1 stats of RAW output.
template <int CIN, int COUT, int TZ, int TY, int INS, int REDUCE, int NORM>
__global__ void __launch_bounds__(512) convmf_k(
    const bf16* __restrict__ act, const bf16* __restrict__ wpk,
    const float2* __restrict__ musc, bf16* __restrict__ out,
    double* __restrict__ pbuf, int D, int H, int W) {
  constexpr int CH = CIN / 8;
  constexpr int HZ = TZ + 2, HY = TY + 2;
  constexpr int HALO = HZ * HY * 18;
  constexpr int MS = TZ * TY / 4;
  constexpr int NS = COUT / 32;
  constexpr int NWT = COUT / 16;
  constexpr int KB = CIN / 32;
  __shared__ short lds[HALO * CIN];
  __shared__ float2 red[8][NS][16];
  const int t = threadIdx.x;
  const int gx0 = blockIdx.x * 16, gy0 = blockIdx.y * TY, gz0 = blockIdx.z * TZ;
  // ---- stage input tile (swizzled; norm+mish applied here when NORM) ----
  const short* actS = (const short*)act;
  for (int cid = t; cid < HALO * CH; cid += 512) {
    int pos = cid / CH, c = cid - pos * CH;
    int hx = pos % 18; int r = pos / 18; int hy = r % HY; int hz = r / HY;
    int gz = gz0 + hz - 1, gy = gy0 + hy - 1, gx = gx0 + hx - 1;
    uint4 v = {0u, 0u, 0u, 0u};
    if (((unsigned)gz < (unsigned)D) & ((unsigned)gy < (unsigned)H) & ((unsigned)gx < (unsigned)W)) {
      size_t vox = (size_t)(gz * H + gy) * W + gx;
      if (INS == 8) { if (c == 0) v = *(const uint4*)(actS + vox * 8); }
      else {
        v = *(const uint4*)(actS + vox * CIN + c * 8);
        if (NORM) {
          short* sp = (short*)&v;
#pragma unroll
          for (int j = 0; j < 8; ++j) {
            float2 mm = musc[c * 8 + j];
            float f = mishf((bfu((unsigned short)sp[j]) - mm.x) * mm.y);
            sp[j] = (short)fbf(f);
          }
        }
      }
    }
    *(uint4*)(lds + pos * CIN + ((c ^ (pos & (CH - 1))) * 8)) = v;
  }
  __syncthreads();
  // ---- compute (R11-proven 4M x 2N) ----
  const int lane = t & 63, wid = t >> 6;
  const int mw = wid & 3, nw = wid >> 2;
  const int lid = lane & 15, kg = lane >> 4;
  f32x4 acc[MS][NS];
#pragma unroll
  for (int ms = 0; ms < MS; ++ms)
#pragma unroll
    for (int n = 0; n < NS; ++n) acc[ms][n] = {0.f, 0.f, 0.f, 0.f};
  int rowpos[MS];
#pragma unroll
  for (int ms = 0; ms < MS; ++ms) {
    int r = mw * MS + ms;
    rowpos[ms] = ((r / TY) * HY + (r % TY)) * 18 + lid;
  }
  const short* wp = (const short*)wpk;
#pragma unroll 1
  for (int kz = 0; kz < 3; ++kz)
#pragma unroll 1
    for (int ky = 0; ky < 3; ++ky) {
      const int delta0 = (kz * HY + ky) * 18;
#pragma unroll
      for (int kx = 0; kx < 3; ++kx) {
        const int off = (kz * 3 + ky) * 3 + kx;
        short8 bq[NS][KB];
#pragma unroll
        for (int n = 0; n < NS; ++n)
#pragma unroll
          for (int kb = 0; kb < KB; ++kb)
            bq[n][kb] = *(const short8*)(wp + ((((size_t)off * NWT + nw * NS + n) * KB + kb) << 9) + lane * 8);
#pragma unroll
        for (int ms = 0; ms < MS; ++ms) {
          int pos = rowpos[ms] + delta0 + kx;
          int sw = pos & (CH - 1);
#pragma unroll
          for (int kb = 0; kb < KB; ++kb) {
            short8 a = *(const short8*)(lds + pos * CIN + (((kb * 4 + kg) ^ sw) * 8));
#pragma unroll
            for (int n = 0; n < NS; ++n)
              acc[ms][n] = __builtin_amdgcn_mfma_f32_16x16x32_bf16(a, bq[n][kb], acc[ms][n], 0, 0, 0);
          }
        }
      }
    }
  // ---- epilogue: C/D layout col=lane&15 (cout), row=(lane>>4)*4+reg (x) ----
  const int xe = kg * 4;
#pragma unroll
  for (int ms = 0; ms < MS; ++ms) {
    int r = mw * MS + ms;
    int z = gz0 + r / TY, y = gy0 + r % TY;
    size_t voxb = (size_t)(z * H + y) * W + gx0;
#pragma unroll
    for (int n = 0; n < NS; ++n) {
      int co = nw * NS * 16 + n * 16 + lid;
#pragma unroll
      for (int rg = 0; rg < 4; ++rg)
        out[(voxb + xe + rg) * COUT + co] = __float2bfloat16(acc[ms][n][rg]);
    }
  }
  // ---- fused InstanceNorm stage-1 partials (f32 acc, deterministic) ----
  if (REDUCE) {
#pragma unroll
    for (int n = 0; n < NS; ++n) {
      float s = 0.f, q = 0.f;
#pragma unroll
      for (int ms = 0; ms < MS; ++ms)
#pragma unroll
        for (int rg = 0; rg < 4; ++rg) {
          float v = acc[ms][n][rg];
          s += v; q += v * v;
        }
      s += __shfl_xor(s, 16); q += __shfl_xor(q, 16);
      s += __shfl_xor(s, 32); q += __shfl_xor(q, 32);
      if (lane < 16) red[wid][n][lane] = make_float2(s, q);
    }
    __syncthreads();
    if (t < COUT) {
      const int nw_ = t / (NS * 16);
      const int rem = t - nw_ * NS * 16;
      const int n_ = rem >> 4, lid_ = rem & 15;
      float S = 0.f, Q = 0.f;
#pragma unroll
      for (int m = 0; m < 4; ++m) {
        float2 v = red[nw_ * 4 + m][n_][lid_];
        S += v.x; Q += v.y;
      }
      const int G = gridDim.x * gridDim.y * gridDim.z;
      const int bid = blockIdx.x + gridDim.x * (blockIdx.y + gridDim.y * blockIdx.z);
      pbuf[((size_t)t * G + bid) * 2 + 0] = (double)S;
      pbuf[((size_t)t * G + bid) * 2 + 1] = (double)Q;
    }
  }
}

// ---------------- conv4 MFMA 16x16x32: raw bufA + norm-in-staging -> vf ------
template <int TZ, int TY>
__global__ void __launch_bounds__(512) conv4mf_k(
    const bf16* __restrict__ act, const bf16* __restrict__ wpk,
    const float2* __restrict__ musc, const float* __restrict__ bias,
    float* __restrict__ vf, int D, int H, int W) {
  constexpr int CH = 4;
  constexpr int HZ = TZ + 2, HY = TY + 2;
  constexpr int HALO = HZ * HY * 18;
  constexpr int MS = TZ * TY / 8;
  __shared__ short lds[HALO * 32];
  const int t = threadIdx.x;
  const int gx0 = blockIdx.x * 16, gy0 = blockIdx.y * TY, gz0 = blockIdx.z * TZ;
  const int N = D * H * W;
  const short* actS = (const short*)act;
  for (int cid = t; cid < HALO * CH; cid += 512) {
    int pos = cid / CH, c = cid - pos * CH;
    int hx = pos % 18; int r = pos / 18; int hy = r % HY; int hz = r / HY;
    int gz = gz0 + hz - 1, gy = gy0 + hy - 1, gx = gx0 + hx - 1;
    uint4 v = {0u, 0u, 0u, 0u};
    if (((unsigned)gz < (unsigned)D) & ((unsigned)gy < (unsigned)H) & ((unsigned)gx < (unsigned)W)) {
      v = *(const uint4*)(actS + ((size_t)(gz * H + gy) * W + gx) * 32 + c * 8);
      short* sp = (short*)&v;
#pragma unroll
      for (int j = 0; j < 8; ++j) {
        float2 mm = musc[c * 8 + j];
        float f = mishf((bfu((unsigned short)sp[j]) - mm.x) * mm.y);
        sp[j] = (short)fbf(f);
      }
    }
    *(uint4*)(lds + pos * 32 + ((c ^ (pos & 3)) * 8)) = v;
  }
  __syncthreads();
  const int lane = t & 63, wid = t >> 6;
  const int lid = lane & 15, kg = lane >> 4;
  f32x4 acc[MS];
#pragma unroll
  for (int ms = 0; ms < MS; ++ms) acc[ms] = {0.f, 0.f, 0.f, 0.f};
  int rowpos[MS];
#pragma unroll
  for (int ms = 0; ms < MS; ++ms) {
    int r = wid * MS + ms;
    rowpos[ms] = ((r / TY) * HY + (r % TY)) * 18 + lid;
  }
  const short* wp = (const short*)wpk;
#pragma unroll 1
  for (int kz = 0; kz < 3; ++kz)
#pragma unroll 1
    for (int ky = 0; ky < 3; ++ky) {
      const int delta0 = (kz * HY + ky) * 18;
#pragma unroll
      for (int kx = 0; kx < 3; ++kx) {
        const int off = (kz * 3 + ky) * 3 + kx;
        short8 b = *(const short8*)(wp + ((size_t)off << 9) + lane * 8);
#pragma unroll
        for (int ms = 0; ms < MS; ++ms) {
          int pos = rowpos[ms] + delta0 + kx;
          int sw = pos & 3;
          short8 a = *(const short8*)(lds + pos * 32 + ((kg ^ sw) * 8));
          acc[ms] = __builtin_amdgcn_mfma_f32_16x16x32_bf16(a, b, acc[ms], 0, 0, 0);
        }
      }
    }
  if (lid < 3) {
    float bs = bias[lid];
#pragma unroll
    for (int ms = 0; ms < MS; ++ms) {
      int r = wid * MS + ms;
      int z = gz0 + r / TY, y = gy0 + r % TY;
      size_t voxb = (size_t)(z * H + y) * W + gx0 + kg * 4;
      float* p = vf + (size_t)lid * N + voxb;
#pragma unroll
      for (int rg = 0; rg < 4; ++rg) p[rg] += acc[ms][rg] + bs;
    }
  }
}

// ---------------- InstanceNorm stage-2 (musc = mean, inv-std) ----------------
__global__ void stage2_k(const double* __restrict__ pbuf, float2* __restrict__ musc,
                         int N, int G) {
  const int c = blockIdx.x;
  double S = 0, Q = 0;
  for (int g = threadIdx.x; g < G; g += 256) {
    S += pbuf[((size_t)c * G + g) * 2 + 0];
    Q += pbuf[((size_t)c * G + g) * 2 + 1];
  }
  for (int off = 32; off > 0; off >>= 1) {
    S += __shfl_down(S, off); Q += __shfl_down(Q, off);
  }
  __shared__ double ls[4], lq[4];
  const int wid = threadIdx.x >> 6, lane = threadIdx.x & 63;
  if (lane == 0) { ls[wid] = S; lq[wid] = Q; }
  __syncthreads();
  if (threadIdx.x == 0) {
    double St = ls[0] + ls[1] + ls[2] + ls[3];
    double Qt = lq[0] + lq[1] + lq[2] + lq[3];
    double m = St / N;
    double var = Qt / N - m * m;
    musc[c] = make_float2((float)m, (float)(1.0 / sqrt(var + 1e-5)));
  }
}

// ---------------- separable 7-tap Gaussian, zero padded ----------------------
template <int AXIS>
__global__ void smooth_k(const float* __restrict__ in, float* __restrict__ out,
                         int D, int H, int W) {
  const int N = D * H * W;
  const int c = blockIdx.y;
  int i = blockIdx.x * 256 + threadIdx.x;
  if (i >= N) return;
  int x = i % W; int t = i / W; int y = t % H; int z = t / H;
  const int coord = AXIS == 0 ? z : AXIS == 1 ? y : x;
  const int len = AXIS == 0 ? D : AXIS == 1 ? H : W;
  const int stride = AXIS == 0 ? H * W : AXIS == 1 ? W : 1;
  const float k1 = 0.60653065971263342f, k2 = 0.13533528323661270f, k3 = 0.011108996538242306f;
  const float kn = 1.f / (1.f + 2.f * (k1 + k2 + k3));
  const float gw[4] = {kn, k1 * kn, k2 * kn, k3 * kn};
  const float* p = in + (size_t)c * N;
  float s = gw[0] * p[i];
#pragma unroll
  for (int tt = 1; tt <= 3; ++tt) {
    if (coord - tt >= 0) s += gw[tt] * p[i - tt * stride];
    if (coord + tt < len) s += gw[tt] * p[i + tt * stride];
  }
  out[(size_t)c * N + i] = s;
}

// ---------------------------------------------------------------------------
extern "C" void kernel_launch(void* const* d_in, const int* in_sizes, int n_in,
                              void* d_out, int out_size, void* d_ws, size_t ws_size,
                              hipStream_t stream) {
  const float* image  = (const float*)d_in[0];
  const float* moving = (const float*)d_in[2];
  const float* w1 = (const float*)d_in[4];
  const float* w2 = (const float*)d_in[5];
  const float* w3 = (const float*)d_in[6];
  const float* w4 = (const float*)d_in[7];
  const float* b4 = (const float*)d_in[8];
  float* out = (float*)d_out;

  const int D1 = 96; const int N1 = D1 * D1 * D1;
  const int D0 = 48; const int N0 = D0 * D0 * D0;

  // ---- workspace layout (~236 MB) ----
  char* wsp = (char*)d_ws;
  double* pbuf  = (double*)wsp;          wsp += (size_t)64 * 13824 * 2 * 8; // 14.2 MB
  float2* musc  = (float2*)wsp;          wsp += 1024;
  bf16* w1p     = (bf16*)wsp;            wsp += 27 * 2 * 1 * 512 * 2;  // frag [off][nwt][kb][512]
  bf16* w2p     = (bf16*)wsp;            wsp += 27 * 4 * 1 * 512 * 2;
  bf16* w3p     = (bf16*)wsp;            wsp += 27 * 2 * 2 * 512 * 2;
  bf16* w4p     = (bf16*)wsp;            wsp += 27 * 1 * 1 * 512 * 2;
  float* si0    = (float*)wsp;           wsp += (size_t)N0 * 4;
  float* smov0  = (float*)wsp;           wsp += (size_t)N0 * 4;
  float* vf0    = (float*)wsp;           wsp += 3 * (size_t)N1 * 4;
  float* vf1    = (float*)wsp;           wsp += 3 * (size_t)N1 * 4;
  bf16* feat    = (bf16*)wsp;            wsp += 8 * (size_t)N1 * 2;  // [vox][8]
  bf16* bufA    = (bf16*)wsp;            wsp += 32 * (size_t)N1 * 2; // [vox][32] raw
  bf16* bufB    = (bf16*)wsp;            wsp += 64 * (size_t)N1 * 2; // [vox][64] raw

  // ---- weight packing (bf16, fragment order) ----
  pack_wf_k<<<(27 * 2 * 512 + 255) / 256, 256, 0, stream>>>(w1, w1p, 2, 1, 32, 5);
  pack_wf_k<<<(27 * 4 * 512 + 255) / 256, 256, 0, stream>>>(w2, w2p, 4, 1, 64, 32);
  pack_wf_k<<<(27 * 4 * 512 + 255) / 256, 256, 0, stream>>>(w3, w3p, 2, 2, 32, 64);
  pack_wf_k<<<(27 * 1 * 512 + 255) / 256, 256, 0, stream>>>(w4, w4p, 1, 1, 3, 32);

  // ---- level 0 setup ----
  down2x_k<<<N0 / 256, 256, 0, stream>>>(image, si0, D0, D0, D0);
  down2x_k<<<N0 / 256, 256, 0, stream>>>(moving, smov0, D0, D0, D0);
  zero_k<<<3 * N0 / 256, 256, 0, stream>>>(vf0, 3 * N0);

  float* vfc = vf0;
  float* vfa = vf1;

  auto run_level = [&](const float* si, const float* smov, int Dd) {
    const int N = Dd * Dd * Dd;
    const int nb = N / 256;
    const dim3 gw(Dd / 8, Dd / 8, Dd / 4);    // warpforce tile 8x8x4
    const dim3 g1(Dd / 16, Dd / 4, Dd / 4);   // conv1/conv2/conv4: 16x4x4
    const dim3 g3(Dd / 16, Dd / 4, Dd / 2);   // conv3: 16x4x2
    const int G1 = g1.x * g1.y * g1.z;
    const int G3 = g3.x * g3.y * g3.z;
    for (int it = 0; it < 2; ++it) {
      warpforce_k<<<gw, 256, 0, stream>>>(smov, vfc, si, feat, Dd, Dd, Dd);

      convmf_k<32, 32, 4, 4, 8, 1, 0><<<g1, 512, 0, stream>>>(feat, w1p, musc, bufA, pbuf, Dd, Dd, Dd);
      stage2_k<<<32, 256, 0, stream>>>(pbuf, musc, N, G1);

      convmf_k<32, 64, 4, 4, 32, 1, 1><<<g1, 512, 0, stream>>>(bufA, w2p, musc, bufB, pbuf, Dd, Dd, Dd);
      stage2_k<<<64, 256, 0, stream>>>(pbuf, musc, N, G1);

      convmf_k<64, 32, 2, 4, 64, 1, 1><<<g3, 512, 0, stream>>>(bufB, w3p, musc, bufA, pbuf, Dd, Dd, Dd);
      stage2_k<<<32, 256, 0, stream>>>(pbuf, musc, N, G3);

      conv4mf_k<4, 4><<<g1, 512, 0, stream>>>(bufA, w4p, musc, b4, vfc, Dd, Dd, Dd);

      smooth_k<0><<<dim3(nb, 3), 256, 0, stream>>>(vfc, vfa, Dd, Dd, Dd);
      smooth_k<1><<<dim3(nb, 3), 256, 0, stream>>>(vfa, vfc, Dd, Dd, Dd);
      smooth_k<2><<<dim3(nb, 3), 256, 0, stream>>>(vfc, vfa, Dd, Dd, Dd);
      { float* tmp = vfc; vfc = vfa; vfa = tmp; }
    }
  };

  // ---- level 0 (48^3) ----
  run_level(si0, smov0, D0);

  // ---- upsample vf to 96^3, scale displacements by 2 ----
  up2x_vf_k<<<dim3(N1 / 256, 3), 256, 0, stream>>>(vfc, vfa, D1, D1, D1);
  { float* tmp = vfc; vfc = vfa; vfa = tmp; }

  // ---- level 1 (96^3) ----
  run_level(image, moving, D1);

  // ---- outputs: warped_full, vf ----
  warp_k<<<N1 / 256, 256, 0, stream>>>(moving, vfc, out, D1, D1, D1);
  copy_k<<<3 * N1 / 256, 256, 0, stream>>>(vfc, out + N1, 3 * N1);
}

// Round 15
// 1357.802 us; speedup vs baseline: 1.2728x; 1.2728x over previous
//
#include <hip/hip_runtime.h>
#include <hip/hip_bf16.h>

// ---------------------------------------------------------------------------
// TrainableVarRegBlock: 2-level demons registration (48^3, 96^3), 2 iters each.
// R11-proven conv path: bf16 MFMA 16x16x32, 4Mx2N waves, fragment-ordered B,
// fused IN stage-1 reduce in conv epilogue, separate BW-bound inorm+fast-mish.
// warp+forces fused (warpforce_k). Force path f32.
// ---------------------------------------------------------------------------

#define DEV __device__ __forceinline__
typedef __hip_bfloat16 bf16;
typedef __attribute__((ext_vector_type(8))) short short8;
typedef __attribute__((ext_vector_type(4))) float f32x4;

DEV float bfu(unsigned int u) {           // bf16 bits -> f32 (exact)
  union { unsigned int i; float f; } x; x.i = u << 16; return x.f;
}
DEV unsigned short fbf(float f) {         // f32 -> bf16 bits (RNE)
  __hip_bfloat16 h = __float2bfloat16(f);
  return __builtin_bit_cast(unsigned short, h);
}

// fast mish: x*tanh(softplus(x)) == x*(u^2+2u)/(u^2+2u+2), u=e^x (exact algebra)
DEV float mishf(float v) {
  if (v > 20.f) return v;
  float u = __expf(v);
  float w = u * (u + 2.f);
  return v * (w / (w + 2.f));
}

// ---------------- small utility kernels ----------------
__global__ void zero_k(float* __restrict__ p, int n) {
  int i = blockIdx.x * 256 + threadIdx.x;
  if (i < n) p[i] = 0.f;
}
__global__ void copy_k(const float* __restrict__ in, float* __restrict__ out, int n) {
  int i = blockIdx.x * 256 + threadIdx.x;
  if (i < n) out[i] = in[i];
}

// 16x16 fragment pack: dst[((off*NWT+nwt)*KB+kb)*512 + lane*8 + j]
// = w[co = nwt*16 + (lane&15)][ci = (kb*4 + (lane>>4))*8 + j]  (zero-padded)
__global__ void pack_wf_k(const float* __restrict__ w, bf16* __restrict__ dst,
                          int NWT, int KB, int COR, int CIR) {
  int idx = blockIdx.x * 256 + threadIdx.x;
  int tot = 27 * NWT * KB * 512;
  if (idx >= tot) return;
  int j = idx & 7;
  int lane = (idx >> 3) & 63;
  int frag = idx >> 9;
  int kb = frag % KB;
  int r2 = frag / KB;
  int nwt = r2 % NWT;
  int off = r2 / NWT;
  int co = nwt * 16 + (lane & 15);
  int ci = (kb * 4 + (lane >> 4)) * 8 + j;
  float v = (co < COR && ci < CIR) ? w[((size_t)co * CIR + ci) * 27 + off] : 0.f;
  dst[idx] = __float2bfloat16(v);
}

// ---------------- resize helpers ----------------
DEV int ds_taps(int i, int n_out, int* j0, float* w) {
  if (i == 0) { *j0 = 0; w[0] = 3.f/7.f; w[1] = 3.f/7.f; w[2] = 1.f/7.f; return 3; }
  if (i == n_out - 1) { *j0 = 2*i - 1; w[0] = 1.f/7.f; w[1] = 3.f/7.f; w[2] = 3.f/7.f; return 3; }
  *j0 = 2*i - 1; w[0] = 0.125f; w[1] = 0.375f; w[2] = 0.375f; w[3] = 0.125f; return 4;
}
DEV void up_taps(int i, int n_in, int* j0, int* j1, float* w0, float* w1) {
  if (i & 1) {
    int k = i >> 1;
    if (k + 1 >= n_in) { *j0 = n_in - 1; *j1 = n_in - 1; *w0 = 1.f; *w1 = 0.f; }
    else { *j0 = k; *j1 = k + 1; *w0 = 0.75f; *w1 = 0.25f; }
  } else {
    int k = i >> 1;
    if (k == 0) { *j0 = 0; *j1 = 0; *w0 = 1.f; *w1 = 0.f; }
    else { *j0 = k - 1; *j1 = k; *w0 = 0.25f; *w1 = 0.75f; }
  }
}

__global__ void down2x_k(const float* __restrict__ in, float* __restrict__ out,
                         int Do, int Ho, int Wo) {
  const int Hi = 2 * Ho, Wi = 2 * Wo;
  const int No = Do * Ho * Wo;
  int i = blockIdx.x * 256 + threadIdx.x;
  if (i >= No) return;
  int xo = i % Wo; int t = i / Wo; int yo = t % Ho; int zo = t / Ho;
  int jz0, jy0, jx0; float wz[4], wy[4], wx[4];
  int cz = ds_taps(zo, Do, &jz0, wz);
  int cy = ds_taps(yo, Ho, &jy0, wy);
  int cx = ds_taps(xo, Wo, &jx0, wx);
  float s = 0.f;
  for (int a = 0; a < cz; ++a) {
    const float* pz = in + (size_t)(jz0 + a) * Hi * Wi;
    for (int b = 0; b < cy; ++b) {
      const float* py = pz + (size_t)(jy0 + b) * Wi;
      float wab = wz[a] * wy[b];
      for (int d = 0; d < cx; ++d) s += wab * wx[d] * py[jx0 + d];
    }
  }
  out[i] = s;
}

__global__ void up2x_vf_k(const float* __restrict__ in, float* __restrict__ out,
                          int Do, int Ho, int Wo) {
  const int Di = Do / 2, Hi = Ho / 2, Wi = Wo / 2;
  const int No = Do * Ho * Wo;
  const int c = blockIdx.y;
  int i = blockIdx.x * 256 + threadIdx.x;
  if (i >= No) return;
  int xo = i % Wo; int t = i / Wo; int yo = t % Ho; int zo = t / Ho;
  int jz0, jz1, jy0, jy1, jx0, jx1; float wz0, wz1, wy0, wy1, wx0, wx1;
  up_taps(zo, Di, &jz0, &jz1, &wz0, &wz1);
  up_taps(yo, Hi, &jy0, &jy1, &wy0, &wy1);
  up_taps(xo, Wi, &jx0, &jx1, &wx0, &wx1);
  const float* p = in + (size_t)c * Di * Hi * Wi;
  float v00 = wx0 * p[(jz0 * Hi + jy0) * Wi + jx0] + wx1 * p[(jz0 * Hi + jy0) * Wi + jx1];
  float v01 = wx0 * p[(jz0 * Hi + jy1) * Wi + jx0] + wx1 * p[(jz0 * Hi + jy1) * Wi + jx1];
  float v10 = wx0 * p[(jz1 * Hi + jy0) * Wi + jx0] + wx1 * p[(jz1 * Hi + jy0) * Wi + jx1];
  float v11 = wx0 * p[(jz1 * Hi + jy1) * Wi + jx0] + wx1 * p[(jz1 * Hi + jy1) * Wi + jx1];
  float s = wz0 * (wy0 * v00 + wy1 * v01) + wz1 * (wy0 * v10 + wy1 * v11);
  out[(size_t)c * No + i] = 2.f * s;
}

// ---------------- warp helper (trilinear, border clamp) ----------------------
DEV float warp1(const float* __restrict__ img, const float* __restrict__ vf,
                int x, int y, int z, size_t i, int D, int H, int W, size_t N) {
  float zc = fminf(fmaxf((float)z + vf[i], 0.f), (float)(D - 1));
  float yc = fminf(fmaxf((float)y + vf[N + i], 0.f), (float)(H - 1));
  float xc = fminf(fmaxf((float)x + vf[2 * N + i], 0.f), (float)(W - 1));
  float zf = floorf(zc), yf = floorf(yc), xf = floorf(xc);
  int z0 = (int)zf, y0 = (int)yf, x0 = (int)xf;
  float wz = zc - zf, wy = yc - yf, wx = xc - xf;
  int z1 = min(z0 + 1, D - 1), y1 = min(y0 + 1, H - 1), x1 = min(x0 + 1, W - 1);
  const int HW = H * W;
  float v000 = img[z0 * HW + y0 * W + x0];
  float v001 = img[z0 * HW + y0 * W + x1];
  float v010 = img[z0 * HW + y1 * W + x0];
  float v011 = img[z0 * HW + y1 * W + x1];
  float v100 = img[z1 * HW + y0 * W + x0];
  float v101 = img[z1 * HW + y0 * W + x1];
  float v110 = img[z1 * HW + y1 * W + x0];
  float v111 = img[z1 * HW + y1 * W + x1];
  return v000 * (1 - wz) * (1 - wy) * (1 - wx)
       + v001 * (1 - wz) * (1 - wy) * wx
       + v010 * (1 - wz) * wy * (1 - wx)
       + v011 * (1 - wz) * wy * wx
       + v100 * wz * (1 - wy) * (1 - wx)
       + v101 * wz * (1 - wy) * wx
       + v110 * wz * wy * (1 - wx)
       + v111 * wz * wy * wx;
}

__global__ void warp_k(const float* __restrict__ img, const float* __restrict__ vf,
                       float* __restrict__ out, int D, int H, int W) {
  const size_t N = (size_t)D * H * W;
  size_t i = (size_t)blockIdx.x * 256 + threadIdx.x;
  if (i >= N) return;
  int x = i % W; int t = i / W; int y = t % H; int z = t / H;
  out[i] = warp1(img, vf, x, y, z, i, D, H, W, N);
}

// ---------------- fused warp + demon forces -> feat [vox][8] bf16 ------------
__global__ void __launch_bounds__(256) warpforce_k(
    const float* __restrict__ img, const float* __restrict__ vf,
    const float* __restrict__ si, bf16* __restrict__ feat, int D, int H, int W) {
  __shared__ float wt[600];
  const size_t N = (size_t)D * H * W;
  const int t = threadIdx.x;
  const int tx = t & 7, ty = (t >> 3) & 7, tz = t >> 6;
  const int gx0 = blockIdx.x * 8, gy0 = blockIdx.y * 8, gz0 = blockIdx.z * 4;
  for (int cid = t; cid < 600; cid += 256) {
    int hx = cid % 10; int r = cid / 10; int hy = r % 10; int hz = r / 10;
    int gz = gz0 + hz - 1, gy = gy0 + hy - 1, gx = gx0 + hx - 1;
    float w = 0.f;
    if (((unsigned)gz < (unsigned)D) & ((unsigned)gy < (unsigned)H) & ((unsigned)gx < (unsigned)W)) {
      size_t i = (size_t)(gz * H + gy) * W + gx;
      w = warp1(img, vf, gx, gy, gz, i, D, H, W, N);
    }
    wt[cid] = w;
  }
  __syncthreads();
  const int x = gx0 + tx, y = gy0 + ty, z = gz0 + tz;
  const size_t i = (size_t)(z * H + y) * W + x;
  const int c = (tz + 1) * 100 + (ty + 1) * 10 + (tx + 1);
  float wv = wt[c];
  float gz = (z == 0) ? (wt[c + 100] - wv) : (z == D - 1) ? (wv - wt[c - 100]) : 0.5f * (wt[c + 100] - wt[c - 100]);
  float gy = (y == 0) ? (wt[c + 10] - wv) : (y == H - 1) ? (wv - wt[c - 10]) : 0.5f * (wt[c + 10] - wt[c - 10]);
  float gx = (x == 0) ? (wt[c + 1] - wv) : (x == W - 1) ? (wv - wt[c - 1]) : 0.5f * (wt[c + 1] - wt[c - 1]);
  float s = si[i];
  float diff = wv - s;
  float denom = gz * gz + gy * gy + gx * gx + diff * diff + 1e-9f;
  short8 o;
  o[0] = (short)fbf((diff * gz) / denom);
  o[1] = (short)fbf((diff * gy) / denom);
  o[2] = (short)fbf((diff * gx) / denom);
  o[3] = (short)fbf(s);
  o[4] = (short)fbf(wv);
  o[5] = 0; o[6] = 0; o[7] = 0;
  *(short8*)((short*)feat + i * 8) = o;
}

// ---------------- MFMA 3^3 conv: 27 shifted GEMMs (R11 structure) -----------
// act [vox][INS or CIN] bf16 -> out [vox][COUT] bf16.
// wpk: FRAGMENT-ordered weights (1KB contiguous per wave-load).
// Block: 512 thr = 8 waves (4 M-groups x 2 N-groups). Tile: TZ x TY x 16 voxels.
// REDUCE: fused InstanceNorm stage-1 from f32 accumulators.
template <int CIN, int COUT, int TZ, int TY, int INS, int REDUCE>
__global__ void __launch_bounds__(512) convmf_k(
    const bf16* __restrict__ act, const bf16* __restrict__ wpk,
    bf16* __restrict__ out, double* __restrict__ pbuf, int D, int H, int W) {
  constexpr int CH = CIN / 8;
  constexpr int HZ = TZ + 2, HY = TY + 2;
  constexpr int HALO = HZ * HY * 18;
  constexpr int MS = TZ * TY / 4;
  constexpr int NS = COUT / 32;
  constexpr int NWT = COUT / 16;
  constexpr int KB = CIN / 32;
  __shared__ short lds[HALO * CIN];
  __shared__ float2 red[8][NS][16];
  const int t = threadIdx.x;
  const int gx0 = blockIdx.x * 16, gy0 = blockIdx.y * TY, gz0 = blockIdx.z * TZ;
  const short* actS = (const short*)act;
  for (int cid = t; cid < HALO * CH; cid += 512) {
    int pos = cid / CH, c = cid - pos * CH;
    int hx = pos % 18; int r = pos / 18; int hy = r % HY; int hz = r / HY;
    int gz = gz0 + hz - 1, gy = gy0 + hy - 1, gx = gx0 + hx - 1;
    uint4 v = {0u, 0u, 0u, 0u};
    if (((unsigned)gz < (unsigned)D) & ((unsigned)gy < (unsigned)H) & ((unsigned)gx < (unsigned)W)) {
      size_t vox = (size_t)(gz * H + gy) * W + gx;
      if (INS == 8) { if (c == 0) v = *(const uint4*)(actS + vox * 8); }
      else v = *(const uint4*)(actS + vox * CIN + c * 8);
    }
    *(uint4*)(lds + pos * CIN + ((c ^ (pos & (CH - 1))) * 8)) = v;
  }
  __syncthreads();
  const int lane = t & 63, wid = t >> 6;
  const int mw = wid & 3, nw = wid >> 2;
  const int lid = lane & 15, kg = lane >> 4;
  f32x4 acc[MS][NS];
#pragma unroll
  for (int ms = 0; ms < MS; ++ms)
#pragma unroll
    for (int n = 0; n < NS; ++n) acc[ms][n] = {0.f, 0.f, 0.f, 0.f};
  int rowpos[MS];
#pragma unroll
  for (int ms = 0; ms < MS; ++ms) {
    int r = mw * MS + ms;
    rowpos[ms] = ((r / TY) * HY + (r % TY)) * 18 + lid;
  }
  const short* wp = (const short*)wpk;
#pragma unroll 1
  for (int kz = 0; kz < 3; ++kz)
#pragma unroll 1
    for (int ky = 0; ky < 3; ++ky) {
      const int delta0 = (kz * HY + ky) * 18;
#pragma unroll
      for (int kx = 0; kx < 3; ++kx) {
        const int off = (kz * 3 + ky) * 3 + kx;
        short8 bq[NS][KB];
#pragma unroll
        for (int n = 0; n < NS; ++n)
#pragma unroll
          for (int kb = 0; kb < KB; ++kb)
            bq[n][kb] = *(const short8*)(wp + ((((size_t)off * NWT + nw * NS + n) * KB + kb) << 9) + lane * 8);
#pragma unroll
        for (int ms = 0; ms < MS; ++ms) {
          int pos = rowpos[ms] + delta0 + kx;
          int sw = pos & (CH - 1);
#pragma unroll
          for (int kb = 0; kb < KB; ++kb) {
            short8 a = *(const short8*)(lds + pos * CIN + (((kb * 4 + kg) ^ sw) * 8));
#pragma unroll
            for (int n = 0; n < NS; ++n)
              acc[ms][n] = __builtin_amdgcn_mfma_f32_16x16x32_bf16(a, bq[n][kb], acc[ms][n], 0, 0, 0);
          }
        }
      }
    }
  const int xe = kg * 4;
#pragma unroll
  for (int ms = 0; ms < MS; ++ms) {
    int r = mw * MS + ms;
    int z = gz0 + r / TY, y = gy0 + r % TY;
    size_t voxb = (size_t)(z * H + y) * W + gx0;
#pragma unroll
    for (int n = 0; n < NS; ++n) {
      int co = nw * NS * 16 + n * 16 + lid;
#pragma unroll
      for (int rg = 0; rg < 4; ++rg)
        out[(voxb + xe + rg) * COUT + co] = __float2bfloat16(acc[ms][n][rg]);
    }
  }
  if (REDUCE) {
#pragma unroll
    for (int n = 0; n < NS; ++n) {
      float s = 0.f, q = 0.f;
#pragma unroll
      for (int ms = 0; ms < MS; ++ms)
#pragma unroll
        for (int rg = 0; rg < 4; ++rg) {
          float v = acc[ms][n][rg];
          s += v; q += v * v;
        }
      s += __shfl_xor(s, 16); q += __shfl_xor(q, 16);
      s += __shfl_xor(s, 32); q += __shfl_xor(q, 32);
      if (lane < 16) red[wid][n][lane] = make_float2(s, q);
    }
    __syncthreads();
    if (t < COUT) {
      const int nw_ = t / (NS * 16);
      const int rem = t - nw_ * NS * 16;
      const int n_ = rem >> 4, lid_ = rem & 15;
      float S = 0.f, Q = 0.f;
#pragma unroll
      for (int m = 0; m < 4; ++m) {
        float2 v = red[nw_ * 4 + m][n_][lid_];
        S += v.x; Q += v.y;
      }
      const int G = gridDim.x * gridDim.y * gridDim.z;
      const int bid = blockIdx.x + gridDim.x * (blockIdx.y + gridDim.y * blockIdx.z);
      pbuf[((size_t)t * G + bid) * 2 + 0] = (double)S;
      pbuf[((size_t)t * G + bid) * 2 + 1] = (double)Q;
    }
  }
}

// ---------------- conv4 MFMA 16x16x32 (R11): normed bufA -> vf f32 [3][N] ----
template <int TZ, int TY>
__global__ void __launch_bounds__(512) conv4mf_k(
    const bf16* __restrict__ act, const bf16* __restrict__ wpk,
    const float* __restrict__ bias, float* __restrict__ vf, int D, int H, int W) {
  constexpr int CH = 4;
  constexpr int HZ = TZ + 2, HY = TY + 2;
  constexpr int HALO = HZ * HY * 18;
  constexpr int MS = TZ * TY / 8;
  __shared__ short lds[HALO * 32];
  const int t = threadIdx.x;
  const int gx0 = blockIdx.x * 16, gy0 = blockIdx.y * TY, gz0 = blockIdx.z * TZ;
  const int N = D * H * W;
  const short* actS = (const short*)act;
  for (int cid = t; cid < HALO * CH; cid += 512) {
    int pos = cid / CH, c = cid - pos * CH;
    int hx = pos % 18; int r = pos / 18; int hy = r % HY; int hz = r / HY;
    int gz = gz0 + hz - 1, gy = gy0 + hy - 1, gx = gx0 + hx - 1;
    uint4 v = {0u, 0u, 0u, 0u};
    if (((unsigned)gz < (unsigned)D) & ((unsigned)gy < (unsigned)H) & ((unsigned)gx < (unsigned)W))
      v = *(const uint4*)(actS + ((size_t)(gz * H + gy) * W + gx) * 32 + c * 8);
    *(uint4*)(lds + pos * 32 + ((c ^ (pos & 3)) * 8)) = v;
  }
  __syncthreads();
  const int lane = t & 63, wid = t >> 6;
  const int lid = lane & 15, kg = lane >> 4;
  f32x4 acc[MS];
#pragma unroll
  for (int ms = 0; ms < MS; ++ms) acc[ms] = {0.f, 0.f, 0.f, 0.f};
  int rowpos[MS];
#pragma unroll
  for (int ms = 0; ms < MS; ++ms) {
    int r = wid * MS + ms;
    rowpos[ms] = ((r / TY) * HY + (r % TY)) * 18 + lid;
  }
  const short* wp = (const short*)wpk;
#pragma unroll 1
  for (int kz = 0; kz < 3; ++kz)
#pragma unroll 1
    for (int ky = 0; ky < 3; ++ky) {
      const int delta0 = (kz * HY + ky) * 18;
#pragma unroll
      for (int kx = 0; kx < 3; ++kx) {
        const int off = (kz * 3 + ky) * 3 + kx;
        short8 b = *(const short8*)(wp + ((size_t)off << 9) + lane * 8);
#pragma unroll
        for (int ms = 0; ms < MS; ++ms) {
          int pos = rowpos[ms] + delta0 + kx;
          int sw = pos & 3;
          short8 a = *(const short8*)(lds + pos * 32 + ((kg ^ sw) * 8));
          acc[ms] = __builtin_amdgcn_mfma_f32_16x16x32_bf16(a, b, acc[ms], 0, 0, 0);
        }
      }
    }
  if (lid < 3) {
    float bs = bias[lid];
#pragma unroll
    for (int ms = 0; ms < MS; ++ms) {
      int r = wid * MS + ms;
      int z = gz0 + r / TY, y = gy0 + r % TY;
      size_t voxb = (size_t)(z * H + y) * W + gx0 + kg * 4;
      float* p = vf + (size_t)lid * N + voxb;
#pragma unroll
      for (int rg = 0; rg < 4; ++rg) p[rg] += acc[ms][rg] + bs;
    }
  }
}

// ---------------- InstanceNorm stage-2 (musc = mean, inv-std) ----------------
__global__ void stage2_k(const double* __restrict__ pbuf, float2* __restrict__ musc,
                         int N, int G) {
  const int c = blockIdx.x;
  double S = 0, Q = 0;
  for (int g = threadIdx.x; g < G; g += 256) {
    S += pbuf[((size_t)c * G + g) * 2 + 0];
    Q += pbuf[((size_t)c * G + g) * 2 + 1];
  }
  for (int off = 32; off > 0; off >>= 1) {
    S += __shfl_down(S, off); Q += __shfl_down(Q, off);
  }
  __shared__ double ls[4], lq[4];
  const int wid = threadIdx.x >> 6, lane = threadIdx.x & 63;
  if (lane == 0) { ls[wid] = S; lq[wid] = Q; }
  __syncthreads();
  if (threadIdx.x == 0) {
    double St = ls[0] + ls[1] + ls[2] + ls[3];
    double Qt = lq[0] + lq[1] + lq[2] + lq[3];
    double m = St / N;
    double var = Qt / N - m * m;
    musc[c] = make_float2((float)m, (float)(1.0 / sqrt(var + 1e-5)));
  }
}

template <int C>
__global__ void inorm_vc_k(bf16* __restrict__ x, const float2* __restrict__ musc, int N) {
  constexpr int CP = C / 2;
  constexpr int VPB = 256 / CP;
  const int cp = threadIdx.x & (CP - 1);
  const int vt = threadIdx.x / CP;
  float2 m0 = musc[2 * cp], m1 = musc[2 * cp + 1];
  unsigned int* p = (unsigned int*)x;
  int v0 = blockIdx.x * (4 * VPB) + vt;
#pragma unroll
  for (int r = 0; r < 4; ++r) {
    int v = v0 + r * VPB;
    size_t idx = (size_t)v * CP + cp;
    unsigned int u = p[idx];
    float a = mishf((bfu(u & 0xffffu) - m0.x) * m0.y);
    float b = mishf((bfu(u >> 16) - m1.x) * m1.y);
    p[idx] = (unsigned int)fbf(a) | ((unsigned int)fbf(b) << 16);
  }
}

// ---------------- separable 7-tap Gaussian, zero padded ----------------------
template <int AXIS>
__global__ void smooth_k(const float* __restrict__ in, float* __restrict__ out,
                         int D, int H, int W) {
  const int N = D * H * W;
  const int c = blockIdx.y;
  int i = blockIdx.x * 256 + threadIdx.x;
  if (i >= N) return;
  int x = i % W; int t = i / W; int y = t % H; int z = t / H;
  const int coord = AXIS == 0 ? z : AXIS == 1 ? y : x;
  const int len = AXIS == 0 ? D : AXIS == 1 ? H : W;
  const int stride = AXIS == 0 ? H * W : AXIS == 1 ? W : 1;
  const float k1 = 0.60653065971263342f, k2 = 0.13533528323661270f, k3 = 0.011108996538242306f;
  const float kn = 1.f / (1.f + 2.f * (k1 + k2 + k3));
  const float gw[4] = {kn, k1 * kn, k2 * kn, k3 * kn};
  const float* p = in + (size_t)c * N;
  float s = gw[0] * p[i];
#pragma unroll
  for (int tt = 1; tt <= 3; ++tt) {
    if (coord - tt >= 0) s += gw[tt] * p[i - tt * stride];
    if (coord + tt < len) s += gw[tt] * p[i + tt * stride];
  }
  out[(size_t)c * N + i] = s;
}

// ---------------------------------------------------------------------------
extern "C" void kernel_launch(void* const* d_in, const int* in_sizes, int n_in,
                              void* d_out, int out_size, void* d_ws, size_t ws_size,
                              hipStream_t stream) {
  const float* image  = (const float*)d_in[0];
  const float* moving = (const float*)d_in[2];
  const float* w1 = (const float*)d_in[4];
  const float* w2 = (const float*)d_in[5];
  const float* w3 = (const float*)d_in[6];
  const float* w4 = (const float*)d_in[7];
  const float* b4 = (const float*)d_in[8];
  float* out = (float*)d_out;

  const int D1 = 96; const int N1 = D1 * D1 * D1;
  const int D0 = 48; const int N0 = D0 * D0 * D0;

  // ---- workspace layout (~236 MB) ----
  char* wsp = (char*)d_ws;
  double* pbuf  = (double*)wsp;          wsp += (size_t)64 * 13824 * 2 * 8; // 14.2 MB
  float2* musc  = (float2*)wsp;          wsp += 1024;
  bf16* w1p     = (bf16*)wsp;            wsp += 27 * 2 * 1 * 512 * 2;
  bf16* w2p     = (bf16*)wsp;            wsp += 27 * 4 * 1 * 512 * 2;
  bf16* w3p     = (bf16*)wsp;            wsp += 27 * 2 * 2 * 512 * 2;
  bf16* w4p     = (bf16*)wsp;            wsp += 27 * 1 * 1 * 512 * 2;
  float* si0    = (float*)wsp;           wsp += (size_t)N0 * 4;
  float* smov0  = (float*)wsp;           wsp += (size_t)N0 * 4;
  float* vf0    = (float*)wsp;           wsp += 3 * (size_t)N1 * 4;
  float* vf1    = (float*)wsp;           wsp += 3 * (size_t)N1 * 4;
  bf16* feat    = (bf16*)wsp;            wsp += 8 * (size_t)N1 * 2;
  bf16* bufA    = (bf16*)wsp;            wsp += 32 * (size_t)N1 * 2;
  bf16* bufB    = (bf16*)wsp;            wsp += 64 * (size_t)N1 * 2;

  // ---- weight packing (bf16, fragment order) ----
  pack_wf_k<<<(27 * 2 * 512 + 255) / 256, 256, 0, stream>>>(w1, w1p, 2, 1, 32, 5);
  pack_wf_k<<<(27 * 4 * 512 + 255) / 256, 256, 0, stream>>>(w2, w2p, 4, 1, 64, 32);
  pack_wf_k<<<(27 * 4 * 512 + 255) / 256, 256, 0, stream>>>(w3, w3p, 2, 2, 32, 64);
  pack_wf_k<<<(27 * 1 * 512 + 255) / 256, 256, 0, stream>>>(w4, w4p, 1, 1, 3, 32);

  // ---- level 0 setup ----
  down2x_k<<<N0 / 256, 256, 0, stream>>>(image, si0, D0, D0, D0);
  down2x_k<<<N0 / 256, 256, 0, stream>>>(moving, smov0, D0, D0, D0);
  zero_k<<<3 * N0 / 256, 256, 0, stream>>>(vf0, 3 * N0);

  float* vfc = vf0;
  float* vfa = vf1;

  auto run_level = [&](const float* si, const float* smov, int Dd) {
    const int N = Dd * Dd * Dd;
    const int nb = N / 256;
    const dim3 gw(Dd / 8, Dd / 8, Dd / 4);    // warpforce tile 8x8x4
    const dim3 g1(Dd / 16, Dd / 4, Dd / 4);   // conv1/conv2/conv4: 16x4x4
    const dim3 g3(Dd / 16, Dd / 4, Dd / 2);   // conv3: 16x4x2
    const int G1 = g1.x * g1.y * g1.z;
    const int G3 = g3.x * g3.y * g3.z;
    for (int it = 0; it < 2; ++it) {
      warpforce_k<<<gw, 256, 0, stream>>>(smov, vfc, si, feat, Dd, Dd, Dd);

      convmf_k<32, 32, 4, 4, 8, 1><<<g1, 512, 0, stream>>>(feat, w1p, bufA, pbuf, Dd, Dd, Dd);
      stage2_k<<<32, 256, 0, stream>>>(pbuf, musc, N, G1);
      inorm_vc_k<32><<<N / 64, 256, 0, stream>>>(bufA, musc, N);

      convmf_k<32, 64, 4, 4, 32, 1><<<g1, 512, 0, stream>>>(bufA, w2p, bufB, pbuf, Dd, Dd, Dd);
      stage2_k<<<64, 256, 0, stream>>>(pbuf, musc, N, G1);
      inorm_vc_k<64><<<N / 32, 256, 0, stream>>>(bufB, musc, N);

      convmf_k<64, 32, 2, 4, 64, 1><<<g3, 512, 0, stream>>>(bufB, w3p, bufA, pbuf, Dd, Dd, Dd);
      stage2_k<<<32, 256, 0, stream>>>(pbuf, musc, N, G3);
      inorm_vc_k<32><<<N / 64, 256, 0, stream>>>(bufA, musc, N);

      conv4mf_k<4, 4><<<g1, 512, 0, stream>>>(bufA, w4p, b4, vfc, Dd, Dd, Dd);

      smooth_k<0><<<dim3(nb, 3), 256, 0, stream>>>(vfc, vfa, Dd, Dd, Dd);
      smooth_k<1><<<dim3(nb, 3), 256, 0, stream>>>(vfa, vfc, Dd, Dd, Dd);
      smooth_k<2><<<dim3(nb, 3), 256, 0, stream>>>(vfc, vfa, Dd, Dd, Dd);
      { float* tmp = vfc; vfc = vfa; vfa = tmp; }
    }
  };

  // ---- level 0 (48^3) ----
  run_level(si0, smov0, D0);

  // ---- upsample vf to 96^3, scale displacements by 2 ----
  up2x_vf_k<<<dim3(N1 / 256, 3), 256, 0, stream>>>(vfc, vfa, D1, D1, D1);
  { float* tmp = vfc; vfc = vfa; vfa = tmp; }

  // ---- level 1 (96^3) ----
  run_level(image, moving, D1);

  // ---- outputs: warped_full, vf ----
  warp_k<<<N1 / 256, 256, 0, stream>>>(moving, vfc, out, D1, D1, D1);
  copy_k<<<3 * N1 / 256, 256, 0, stream>>>(vfc, out + N1, 3 * N1);
}

// Round 16
// 1271.455 us; speedup vs baseline: 1.3592x; 1.0679x over previous
//
#include <hip/hip_runtime.h>
#include <hip/hip_bf16.h>

// ---------------------------------------------------------------------------
// TrainableVarRegBlock: 2-level demons registration (48^3, 96^3), 2 iters each.
// R11-proven conv path: bf16 MFMA 16x16x32, 4Mx2N waves, fragment-ordered B,
// fused IN stage-1 reduce in conv epilogue, separate BW-bound inorm+fast-mish.
// conv1 uses 4-taps-per-MFMA K-packing (feat has only 5 real channels).
// warp+forces fused (warpforce_k). Force path f32.
// ---------------------------------------------------------------------------

#define DEV __device__ __forceinline__
typedef __hip_bfloat16 bf16;
typedef __attribute__((ext_vector_type(8))) short short8;
typedef __attribute__((ext_vector_type(4))) float f32x4;

DEV float bfu(unsigned int u) {           // bf16 bits -> f32 (exact)
  union { unsigned int i; float f; } x; x.i = u << 16; return x.f;
}
DEV unsigned short fbf(float f) {         // f32 -> bf16 bits (RNE)
  __hip_bfloat16 h = __float2bfloat16(f);
  return __builtin_bit_cast(unsigned short, h);
}

// fast mish: x*tanh(softplus(x)) == x*(u^2+2u)/(u^2+2u+2), u=e^x (exact algebra)
DEV float mishf(float v) {
  if (v > 20.f) return v;
  float u = __expf(v);
  float w = u * (u + 2.f);
  return v * (w / (w + 2.f));
}

// ---------------- small utility kernels ----------------
__global__ void zero_k(float* __restrict__ p, int n) {
  int i = blockIdx.x * 256 + threadIdx.x;
  if (i < n) p[i] = 0.f;
}
__global__ void copy_k(const float* __restrict__ in, float* __restrict__ out, int n) {
  int i = blockIdx.x * 256 + threadIdx.x;
  if (i < n) out[i] = in[i];
}

// 16x16 fragment pack: dst[((off*NWT+nwt)*KB+kb)*512 + lane*8 + j]
// = w[co = nwt*16 + (lane&15)][ci = (kb*4 + (lane>>4))*8 + j]  (zero-padded)
__global__ void pack_wf_k(const float* __restrict__ w, bf16* __restrict__ dst,
                          int NWT, int KB, int COR, int CIR) {
  int idx = blockIdx.x * 256 + threadIdx.x;
  int tot = 27 * NWT * KB * 512;
  if (idx >= tot) return;
  int j = idx & 7;
  int lane = (idx >> 3) & 63;
  int frag = idx >> 9;
  int kb = frag % KB;
  int r2 = frag / KB;
  int nwt = r2 % NWT;
  int off = r2 / NWT;
  int co = nwt * 16 + (lane & 15);
  int ci = (kb * 4 + (lane >> 4)) * 8 + j;
  float v = (co < COR && ci < CIR) ? w[((size_t)co * CIR + ci) * 27 + off] : 0.f;
  dst[idx] = __float2bfloat16(v);
}

// conv1 4-tap K-packed weights: dst[(rd*2+nw)*512 + lane*8 + j]
// = w1[co = nw*16 + (lane&15)][ci = j][tap = rd*4 + (lane>>4)]  (zero-padded)
__global__ void pack_w1p_k(const float* __restrict__ w, bf16* __restrict__ dst) {
  int idx = blockIdx.x * 256 + threadIdx.x;
  if (idx >= 7 * 2 * 512) return;
  int j = idx & 7;
  int lane = (idx >> 3) & 63;
  int frag = idx >> 9;
  int nw = frag & 1;
  int rd = frag >> 1;
  int co = nw * 16 + (lane & 15);
  int tap = rd * 4 + (lane >> 4);
  float v = (tap < 27 && j < 5) ? w[((size_t)co * 5 + j) * 27 + tap] : 0.f;
  dst[idx] = __float2bfloat16(v);
}

// ---------------- resize helpers ----------------
DEV int ds_taps(int i, int n_out, int* j0, float* w) {
  if (i == 0) { *j0 = 0; w[0] = 3.f/7.f; w[1] = 3.f/7.f; w[2] = 1.f/7.f; return 3; }
  if (i == n_out - 1) { *j0 = 2*i - 1; w[0] = 1.f/7.f; w[1] = 3.f/7.f; w[2] = 3.f/7.f; return 3; }
  *j0 = 2*i - 1; w[0] = 0.125f; w[1] = 0.375f; w[2] = 0.375f; w[3] = 0.125f; return 4;
}
DEV void up_taps(int i, int n_in, int* j0, int* j1, float* w0, float* w1) {
  if (i & 1) {
    int k = i >> 1;
    if (k + 1 >= n_in) { *j0 = n_in - 1; *j1 = n_in - 1; *w0 = 1.f; *w1 = 0.f; }
    else { *j0 = k; *j1 = k + 1; *w0 = 0.75f; *w1 = 0.25f; }
  } else {
    int k = i >> 1;
    if (k == 0) { *j0 = 0; *j1 = 0; *w0 = 1.f; *w1 = 0.f; }
    else { *j0 = k - 1; *j1 = k; *w0 = 0.25f; *w1 = 0.75f; }
  }
}

__global__ void down2x_k(const float* __restrict__ in, float* __restrict__ out,
                         int Do, int Ho, int Wo) {
  const int Hi = 2 * Ho, Wi = 2 * Wo;
  const int No = Do * Ho * Wo;
  int i = blockIdx.x * 256 + threadIdx.x;
  if (i >= No) return;
  int xo = i % Wo; int t = i / Wo; int yo = t % Ho; int zo = t / Ho;
  int jz0, jy0, jx0; float wz[4], wy[4], wx[4];
  int cz = ds_taps(zo, Do, &jz0, wz);
  int cy = ds_taps(yo, Ho, &jy0, wy);
  int cx = ds_taps(xo, Wo, &jx0, wx);
  float s = 0.f;
  for (int a = 0; a < cz; ++a) {
    const float* pz = in + (size_t)(jz0 + a) * Hi * Wi;
    for (int b = 0; b < cy; ++b) {
      const float* py = pz + (size_t)(jy0 + b) * Wi;
      float wab = wz[a] * wy[b];
      for (int d = 0; d < cx; ++d) s += wab * wx[d] * py[jx0 + d];
    }
  }
  out[i] = s;
}

__global__ void up2x_vf_k(const float* __restrict__ in, float* __restrict__ out,
                          int Do, int Ho, int Wo) {
  const int Di = Do / 2, Hi = Ho / 2, Wi = Wo / 2;
  const int No = Do * Ho * Wo;
  const int c = blockIdx.y;
  int i = blockIdx.x * 256 + threadIdx.x;
  if (i >= No) return;
  int xo = i % Wo; int t = i / Wo; int yo = t % Ho; int zo = t / Ho;
  int jz0, jz1, jy0, jy1, jx0, jx1; float wz0, wz1, wy0, wy1, wx0, wx1;
  up_taps(zo, Di, &jz0, &jz1, &wz0, &wz1);
  up_taps(yo, Hi, &jy0, &jy1, &wy0, &wy1);
  up_taps(xo, Wi, &jx0, &jx1, &wx0, &wx1);
  const float* p = in + (size_t)c * Di * Hi * Wi;
  float v00 = wx0 * p[(jz0 * Hi + jy0) * Wi + jx0] + wx1 * p[(jz0 * Hi + jy0) * Wi + jx1];
  float v01 = wx0 * p[(jz0 * Hi + jy1) * Wi + jx0] + wx1 * p[(jz0 * Hi + jy1) * Wi + jx1];
  float v10 = wx0 * p[(jz1 * Hi + jy0) * Wi + jx0] + wx1 * p[(jz1 * Hi + jy0) * Wi + jx1];
  float v11 = wx0 * p[(jz1 * Hi + jy1) * Wi + jx0] + wx1 * p[(jz1 * Hi + jy1) * Wi + jx1];
  float s = wz0 * (wy0 * v00 + wy1 * v01) + wz1 * (wy0 * v10 + wy1 * v11);
  out[(size_t)c * No + i] = 2.f * s;
}

// ---------------- warp helper (trilinear, border clamp) ----------------------
DEV float warp1(const float* __restrict__ img, const float* __restrict__ vf,
                int x, int y, int z, size_t i, int D, int H, int W, size_t N) {
  float zc = fminf(fmaxf((float)z + vf[i], 0.f), (float)(D - 1));
  float yc = fminf(fmaxf((float)y + vf[N + i], 0.f), (float)(H - 1));
  float xc = fminf(fmaxf((float)x + vf[2 * N + i], 0.f), (float)(W - 1));
  float zf = floorf(zc), yf = floorf(yc), xf = floorf(xc);
  int z0 = (int)zf, y0 = (int)yf, x0 = (int)xf;
  float wz = zc - zf, wy = yc - yf, wx = xc - xf;
  int z1 = min(z0 + 1, D - 1), y1 = min(y0 + 1, H - 1), x1 = min(x0 + 1, W - 1);
  const int HW = H * W;
  float v000 = img[z0 * HW + y0 * W + x0];
  float v001 = img[z0 * HW + y0 * W + x1];
  float v010 = img[z0 * HW + y1 * W + x0];
  float v011 = img[z0 * HW + y1 * W + x1];
  float v100 = img[z1 * HW + y0 * W + x0];
  float v101 = img[z1 * HW + y0 * W + x1];
  float v110 = img[z1 * HW + y1 * W + x0];
  float v111 = img[z1 * HW + y1 * W + x1];
  return v000 * (1 - wz) * (1 - wy) * (1 - wx)
       + v001 * (1 - wz) * (1 - wy) * wx
       + v010 * (1 - wz) * wy * (1 - wx)
       + v011 * (1 - wz) * wy * wx
       + v100 * wz * (1 - wy) * (1 - wx)
       + v101 * wz * (1 - wy) * wx
       + v110 * wz * wy * (1 - wx)
       + v111 * wz * wy * wx;
}

__global__ void warp_k(const float* __restrict__ img, const float* __restrict__ vf,
                       float* __restrict__ out, int D, int H, int W) {
  const size_t N = (size_t)D * H * W;
  size_t i = (size_t)blockIdx.x * 256 + threadIdx.x;
  if (i >= N) return;
  int x = i % W; int t = i / W; int y = t % H; int z = t / H;
  out[i] = warp1(img, vf, x, y, z, i, D, H, W, N);
}

// ---------------- fused warp + demon forces -> feat [vox][8] bf16 ------------
__global__ void __launch_bounds__(256) warpforce_k(
    const float* __restrict__ img, const float* __restrict__ vf,
    const float* __restrict__ si, bf16* __restrict__ feat, int D, int H, int W) {
  __shared__ float wt[600];
  const size_t N = (size_t)D * H * W;
  const int t = threadIdx.x;
  const int tx = t & 7, ty = (t >> 3) & 7, tz = t >> 6;
  const int gx0 = blockIdx.x * 8, gy0 = blockIdx.y * 8, gz0 = blockIdx.z * 4;
  for (int cid = t; cid < 600; cid += 256) {
    int hx = cid % 10; int r = cid / 10; int hy = r % 10; int hz = r / 10;
    int gz = gz0 + hz - 1, gy = gy0 + hy - 1, gx = gx0 + hx - 1;
    float w = 0.f;
    if (((unsigned)gz < (unsigned)D) & ((unsigned)gy < (unsigned)H) & ((unsigned)gx < (unsigned)W)) {
      size_t i = (size_t)(gz * H + gy) * W + gx;
      w = warp1(img, vf, gx, gy, gz, i, D, H, W, N);
    }
    wt[cid] = w;
  }
  __syncthreads();
  const int x = gx0 + tx, y = gy0 + ty, z = gz0 + tz;
  const size_t i = (size_t)(z * H + y) * W + x;
  const int c = (tz + 1) * 100 + (ty + 1) * 10 + (tx + 1);
  float wv = wt[c];
  float gz = (z == 0) ? (wt[c + 100] - wv) : (z == D - 1) ? (wv - wt[c - 100]) : 0.5f * (wt[c + 100] - wt[c - 100]);
  float gy = (y == 0) ? (wt[c + 10] - wv) : (y == H - 1) ? (wv - wt[c - 10]) : 0.5f * (wt[c + 10] - wt[c - 10]);
  float gx = (x == 0) ? (wt[c + 1] - wv) : (x == W - 1) ? (wv - wt[c - 1]) : 0.5f * (wt[c + 1] - wt[c - 1]);
  float s = si[i];
  float diff = wv - s;
  float denom = gz * gz + gy * gy + gx * gx + diff * diff + 1e-9f;
  short8 o;
  o[0] = (short)fbf((diff * gz) / denom);
  o[1] = (short)fbf((diff * gy) / denom);
  o[2] = (short)fbf((diff * gx) / denom);
  o[3] = (short)fbf(s);
  o[4] = (short)fbf(wv);
  o[5] = 0; o[6] = 0; o[7] = 0;
  *(short8*)((short*)feat + i * 8) = o;
}

// ---------------- conv1 K-packed: feat [vox][8] -> bufA [vox][32] raw --------
// 4 taps per MFMA: lane-group kg reads feat at tap-(4r+kg)'s offset into
// k-slots kg*8..kg*8+7; B holds w1[co][ci=j][tap=4r+kg]. 7 rounds cover 27 taps.
template <int TZ, int TY>
__global__ void __launch_bounds__(512) conv1p_k(
    const bf16* __restrict__ feat, const bf16* __restrict__ wpk,
    bf16* __restrict__ out, double* __restrict__ pbuf, int D, int H, int W) {
  constexpr int HZ = TZ + 2, HY = TY + 2;
  constexpr int HALO = HZ * HY * 18;
  constexpr int MS = TZ * TY / 4;
  __shared__ short lds[HALO * 8];
  __shared__ float2 red[8][1][16];
  const int t = threadIdx.x;
  const int gx0 = blockIdx.x * 16, gy0 = blockIdx.y * TY, gz0 = blockIdx.z * TZ;
  const short* featS = (const short*)feat;
  for (int pos = t; pos < HALO; pos += 512) {
    int hx = pos % 18; int r = pos / 18; int hy = r % HY; int hz = r / HY;
    int gz = gz0 + hz - 1, gy = gy0 + hy - 1, gx = gx0 + hx - 1;
    uint4 v = {0u, 0u, 0u, 0u};
    if (((unsigned)gz < (unsigned)D) & ((unsigned)gy < (unsigned)H) & ((unsigned)gx < (unsigned)W))
      v = *(const uint4*)(featS + ((size_t)(gz * H + gy) * W + gx) * 8);
    *(uint4*)(lds + pos * 8) = v;
  }
  __syncthreads();
  const int lane = t & 63, wid = t >> 6;
  const int mw = wid & 3, nw = wid >> 2;
  const int lid = lane & 15, kg = lane >> 4;
  f32x4 acc[MS];
#pragma unroll
  for (int ms = 0; ms < MS; ++ms) acc[ms] = {0.f, 0.f, 0.f, 0.f};
  int rowpos[MS];
#pragma unroll
  for (int ms = 0; ms < MS; ++ms) {
    int r = mw * MS + ms;
    rowpos[ms] = ((r / TY) * HY + (r % TY)) * 18 + lid;
  }
  const short* wp = (const short*)wpk;
#pragma unroll
  for (int rd = 0; rd < 7; ++rd) {
    int tap = rd * 4 + kg;
    int tp = tap > 26 ? 26 : tap;             // clamp for addressing (B slot zero)
    int kz = tp / 9, ky = (tp / 3) % 3, kx = tp % 3;
    int delta = (kz * HY + ky) * 18 + kx;
    short8 b = *(const short8*)(wp + ((size_t)(rd * 2 + nw) << 9) + lane * 8);
#pragma unroll
    for (int ms = 0; ms < MS; ++ms) {
      short8 a = *(const short8*)(lds + (rowpos[ms] + delta) * 8);
      acc[ms] = __builtin_amdgcn_mfma_f32_16x16x32_bf16(a, b, acc[ms], 0, 0, 0);
    }
  }
  // ---- epilogue: col=lane&15 (cout), row=(lane>>4)*4+reg (x) ----
  const int xe = kg * 4;
#pragma unroll
  for (int ms = 0; ms < MS; ++ms) {
    int r = mw * MS + ms;
    int z = gz0 + r / TY, y = gy0 + r % TY;
    size_t voxb = (size_t)(z * H + y) * W + gx0;
    int co = nw * 16 + lid;
#pragma unroll
    for (int rg = 0; rg < 4; ++rg)
      out[(voxb + xe + rg) * 32 + co] = __float2bfloat16(acc[ms][rg]);
  }
  // ---- fused InstanceNorm stage-1 partials ----
  {
    float s = 0.f, q = 0.f;
#pragma unroll
    for (int ms = 0; ms < MS; ++ms)
#pragma unroll
      for (int rg = 0; rg < 4; ++rg) {
        float v = acc[ms][rg];
        s += v; q += v * v;
      }
    s += __shfl_xor(s, 16); q += __shfl_xor(q, 16);
    s += __shfl_xor(s, 32); q += __shfl_xor(q, 32);
    if (lane < 16) red[wid][0][lane] = make_float2(s, q);
    __syncthreads();
    if (t < 32) {
      const int nw_ = t >> 4, lid_ = t & 15;
      float S = 0.f, Q = 0.f;
#pragma unroll
      for (int m = 0; m < 4; ++m) {
        float2 v = red[nw_ * 4 + m][0][lid_];
        S += v.x; Q += v.y;
      }
      const int G = gridDim.x * gridDim.y * gridDim.z;
      const int bid = blockIdx.x + gridDim.x * (blockIdx.y + gridDim.y * blockIdx.z);
      pbuf[((size_t)t * G + bid) * 2 + 0] = (double)S;
      pbuf[((size_t)t * G + bid) * 2 + 1] = (double)Q;
    }
  }
}

// ---------------- MFMA 3^3 conv: 27 shifted GEMMs (R11 structure) -----------
template <int CIN, int COUT, int TZ, int TY, int INS, int REDUCE>
__global__ void __launch_bounds__(512) convmf_k(
    const bf16* __restrict__ act, const bf16* __restrict__ wpk,
    bf16* __restrict__ out, double* __restrict__ pbuf, int D, int H, int W) {
  constexpr int CH = CIN / 8;
  constexpr int HZ = TZ + 2, HY = TY + 2;
  constexpr int HALO = HZ * HY * 18;
  constexpr int MS = TZ * TY / 4;
  constexpr int NS = COUT / 32;
  constexpr int NWT = COUT / 16;
  constexpr int KB = CIN / 32;
  __shared__ short lds[HALO * CIN];
  __shared__ float2 red[8][NS][16];
  const int t = threadIdx.x;
  const int gx0 = blockIdx.x * 16, gy0 = blockIdx.y * TY, gz0 = blockIdx.z * TZ;
  const short* actS = (const short*)act;
  for (int cid = t; cid < HALO * CH; cid += 512) {
    int pos = cid / CH, c = cid - pos * CH;
    int hx = pos % 18; int r = pos / 18; int hy = r % HY; int hz = r / HY;
    int gz = gz0 + hz - 1, gy = gy0 + hy - 1, gx = gx0 + hx - 1;
    uint4 v = {0u, 0u, 0u, 0u};
    if (((unsigned)gz < (unsigned)D) & ((unsigned)gy < (unsigned)H) & ((unsigned)gx < (unsigned)W)) {
      size_t vox = (size_t)(gz * H + gy) * W + gx;
      if (INS == 8) { if (c == 0) v = *(const uint4*)(actS + vox * 8); }
      else v = *(const uint4*)(actS + vox * CIN + c * 8);
    }
    *(uint4*)(lds + pos * CIN + ((c ^ (pos & (CH - 1))) * 8)) = v;
  }
  __syncthreads();
  const int lane = t & 63, wid = t >> 6;
  const int mw = wid & 3, nw = wid >> 2;
  const int lid = lane & 15, kg = lane >> 4;
  f32x4 acc[MS][NS];
#pragma unroll
  for (int ms = 0; ms < MS; ++ms)
#pragma unroll
    for (int n = 0; n < NS; ++n) acc[ms][n] = {0.f, 0.f, 0.f, 0.f};
  int rowpos[MS];
#pragma unroll
  for (int ms = 0; ms < MS; ++ms) {
    int r = mw * MS + ms;
    rowpos[ms] = ((r / TY) * HY + (r % TY)) * 18 + lid;
  }
  const short* wp = (const short*)wpk;
#pragma unroll 1
  for (int kz = 0; kz < 3; ++kz)
#pragma unroll 1
    for (int ky = 0; ky < 3; ++ky) {
      const int delta0 = (kz * HY + ky) * 18;
#pragma unroll
      for (int kx = 0; kx < 3; ++kx) {
        const int off = (kz * 3 + ky) * 3 + kx;
        short8 bq[NS][KB];
#pragma unroll
        for (int n = 0; n < NS; ++n)
#pragma unroll
          for (int kb = 0; kb < KB; ++kb)
            bq[n][kb] = *(const short8*)(wp + ((((size_t)off * NWT + nw * NS + n) * KB + kb) << 9) + lane * 8);
#pragma unroll
        for (int ms = 0; ms < MS; ++ms) {
          int pos = rowpos[ms] + delta0 + kx;
          int sw = pos & (CH - 1);
#pragma unroll
          for (int kb = 0; kb < KB; ++kb) {
            short8 a = *(const short8*)(lds + pos * CIN + (((kb * 4 + kg) ^ sw) * 8));
#pragma unroll
            for (int n = 0; n < NS; ++n)
              acc[ms][n] = __builtin_amdgcn_mfma_f32_16x16x32_bf16(a, bq[n][kb], acc[ms][n], 0, 0, 0);
          }
        }
      }
    }
  const int xe = kg * 4;
#pragma unroll
  for (int ms = 0; ms < MS; ++ms) {
    int r = mw * MS + ms;
    int z = gz0 + r / TY, y = gy0 + r % TY;
    size_t voxb = (size_t)(z * H + y) * W + gx0;
#pragma unroll
    for (int n = 0; n < NS; ++n) {
      int co = nw * NS * 16 + n * 16 + lid;
#pragma unroll
      for (int rg = 0; rg < 4; ++rg)
        out[(voxb + xe + rg) * COUT + co] = __float2bfloat16(acc[ms][n][rg]);
    }
  }
  if (REDUCE) {
#pragma unroll
    for (int n = 0; n < NS; ++n) {
      float s = 0.f, q = 0.f;
#pragma unroll
      for (int ms = 0; ms < MS; ++ms)
#pragma unroll
        for (int rg = 0; rg < 4; ++rg) {
          float v = acc[ms][n][rg];
          s += v; q += v * v;
        }
      s += __shfl_xor(s, 16); q += __shfl_xor(q, 16);
      s += __shfl_xor(s, 32); q += __shfl_xor(q, 32);
      if (lane < 16) red[wid][n][lane] = make_float2(s, q);
    }
    __syncthreads();
    if (t < COUT) {
      const int nw_ = t / (NS * 16);
      const int rem = t - nw_ * NS * 16;
      const int n_ = rem >> 4, lid_ = rem & 15;
      float S = 0.f, Q = 0.f;
#pragma unroll
      for (int m = 0; m < 4; ++m) {
        float2 v = red[nw_ * 4 + m][n_][lid_];
        S += v.x; Q += v.y;
      }
      const int G = gridDim.x * gridDim.y * gridDim.z;
      const int bid = blockIdx.x + gridDim.x * (blockIdx.y + gridDim.y * blockIdx.z);
      pbuf[((size_t)t * G + bid) * 2 + 0] = (double)S;
      pbuf[((size_t)t * G + bid) * 2 + 1] = (double)Q;
    }
  }
}

// ---------------- conv4 MFMA 16x16x32 (R11): normed bufA -> vf f32 [3][N] ----
template <int TZ, int TY>
__global__ void __launch_bounds__(512) conv4mf_k(
    const bf16* __restrict__ act, const bf16* __restrict__ wpk,
    const float* __restrict__ bias, float* __restrict__ vf, int D, int H, int W) {
  constexpr int CH = 4;
  constexpr int HZ = TZ + 2, HY = TY + 2;
  constexpr int HALO = HZ * HY * 18;
  constexpr int MS = TZ * TY / 8;
  __shared__ short lds[HALO * 32];
  const int t = threadIdx.x;
  const int gx0 = blockIdx.x * 16, gy0 = blockIdx.y * TY, gz0 = blockIdx.z * TZ;
  const int N = D * H * W;
  const short* actS = (const short*)act;
  for (int cid = t; cid < HALO * CH; cid += 512) {
    int pos = cid / CH, c = cid - pos * CH;
    int hx = pos % 18; int r = pos / 18; int hy = r % HY; int hz = r / HY;
    int gz = gz0 + hz - 1, gy = gy0 + hy - 1, gx = gx0 + hx - 1;
    uint4 v = {0u, 0u, 0u, 0u};
    if (((unsigned)gz < (unsigned)D) & ((unsigned)gy < (unsigned)H) & ((unsigned)gx < (unsigned)W))
      v = *(const uint4*)(actS + ((size_t)(gz * H + gy) * W + gx) * 32 + c * 8);
    *(uint4*)(lds + pos * 32 + ((c ^ (pos & 3)) * 8)) = v;
  }
  __syncthreads();
  const int lane = t & 63, wid = t >> 6;
  const int lid = lane & 15, kg = lane >> 4;
  f32x4 acc[MS];
#pragma unroll
  for (int ms = 0; ms < MS; ++ms) acc[ms] = {0.f, 0.f, 0.f, 0.f};
  int rowpos[MS];
#pragma unroll
  for (int ms = 0; ms < MS; ++ms) {
    int r = wid * MS + ms;
    rowpos[ms] = ((r / TY) * HY + (r % TY)) * 18 + lid;
  }
  const short* wp = (const short*)wpk;
#pragma unroll 1
  for (int kz = 0; kz < 3; ++kz)
#pragma unroll 1
    for (int ky = 0; ky < 3; ++ky) {
      const int delta0 = (kz * HY + ky) * 18;
#pragma unroll
      for (int kx = 0; kx < 3; ++kx) {
        const int off = (kz * 3 + ky) * 3 + kx;
        short8 b = *(const short8*)(wp + ((size_t)off << 9) + lane * 8);
#pragma unroll
        for (int ms = 0; ms < MS; ++ms) {
          int pos = rowpos[ms] + delta0 + kx;
          int sw = pos & 3;
          short8 a = *(const short8*)(lds + pos * 32 + ((kg ^ sw) * 8));
          acc[ms] = __builtin_amdgcn_mfma_f32_16x16x32_bf16(a, b, acc[ms], 0, 0, 0);
        }
      }
    }
  if (lid < 3) {
    float bs = bias[lid];
#pragma unroll
    for (int ms = 0; ms < MS; ++ms) {
      int r = wid * MS + ms;
      int z = gz0 + r / TY, y = gy0 + r % TY;
      size_t voxb = (size_t)(z * H + y) * W + gx0 + kg * 4;
      float* p = vf + (size_t)lid * N + voxb;
#pragma unroll
      for (int rg = 0; rg < 4; ++rg) p[rg] += acc[ms][rg] + bs;
    }
  }
}

// ---------------- InstanceNorm stage-2 (musc = mean, inv-std) ----------------
__global__ void stage2_k(const double* __restrict__ pbuf, float2* __restrict__ musc,
                         int N, int G) {
  const int c = blockIdx.x;
  double S = 0, Q = 0;
  for (int g = threadIdx.x; g < G; g += 256) {
    S += pbuf[((size_t)c * G + g) * 2 + 0];
    Q += pbuf[((size_t)c * G + g) * 2 + 1];
  }
  for (int off = 32; off > 0; off >>= 1) {
    S += __shfl_down(S, off); Q += __shfl_down(Q, off);
  }
  __shared__ double ls[4], lq[4];
  const int wid = threadIdx.x >> 6, lane = threadIdx.x & 63;
  if (lane == 0) { ls[wid] = S; lq[wid] = Q; }
  __syncthreads();
  if (threadIdx.x == 0) {
    double St = ls[0] + ls[1] + ls[2] + ls[3];
    double Qt = lq[0] + lq[1] + lq[2] + lq[3];
    double m = St / N;
    double var = Qt / N - m * m;
    musc[c] = make_float2((float)m, (float)(1.0 / sqrt(var + 1e-5)));
  }
}

template <int C>
__global__ void inorm_vc_k(bf16* __restrict__ x, const float2* __restrict__ musc, int N) {
  constexpr int CP = C / 2;
  constexpr int VPB = 256 / CP;
  const int cp = threadIdx.x & (CP - 1);
  const int vt = threadIdx.x / CP;
  float2 m0 = musc[2 * cp], m1 = musc[2 * cp + 1];
  unsigned int* p = (unsigned int*)x;
  int v0 = blockIdx.x * (4 * VPB) + vt;
#pragma unroll
  for (int r = 0; r < 4; ++r) {
    int v = v0 + r * VPB;
    size_t idx = (size_t)v * CP + cp;
    unsigned int u = p[idx];
    float a = mishf((bfu(u & 0xffffu) - m0.x) * m0.y);
    float b = mishf((bfu(u >> 16) - m1.x) * m1.y);
    p[idx] = (unsigned int)fbf(a) | ((unsigned int)fbf(b) << 16);
  }
}

// ---------------- separable 7-tap Gaussian, zero padded ----------------------
template <int AXIS>
__global__ void smooth_k(const float* __restrict__ in, float* __restrict__ out,
                         int D, int H, int W) {
  const int N = D * H * W;
  const int c = blockIdx.y;
  int i = blockIdx.x * 256 + threadIdx.x;
  if (i >= N) return;
  int x = i % W; int t = i / W; int y = t % H; int z = t / H;
  const int coord = AXIS == 0 ? z : AXIS == 1 ? y : x;
  const int len = AXIS == 0 ? D : AXIS == 1 ? H : W;
  const int stride = AXIS == 0 ? H * W : AXIS == 1 ? W : 1;
  const float k1 = 0.60653065971263342f, k2 = 0.13533528323661270f, k3 = 0.011108996538242306f;
  const float kn = 1.f / (1.f + 2.f * (k1 + k2 + k3));
  const float gw[4] = {kn, k1 * kn, k2 * kn, k3 * kn};
  const float* p = in + (size_t)c * N;
  float s = gw[0] * p[i];
#pragma unroll
  for (int tt = 1; tt <= 3; ++tt) {
    if (coord - tt >= 0) s += gw[tt] * p[i - tt * stride];
    if (coord + tt < len) s += gw[tt] * p[i + tt * stride];
  }
  out[(size_t)c * N + i] = s;
}

// ---------------------------------------------------------------------------
extern "C" void kernel_launch(void* const* d_in, const int* in_sizes, int n_in,
                              void* d_out, int out_size, void* d_ws, size_t ws_size,
                              hipStream_t stream) {
  const float* image  = (const float*)d_in[0];
  const float* moving = (const float*)d_in[2];
  const float* w1 = (const float*)d_in[4];
  const float* w2 = (const float*)d_in[5];
  const float* w3 = (const float*)d_in[6];
  const float* w4 = (const float*)d_in[7];
  const float* b4 = (const float*)d_in[8];
  float* out = (float*)d_out;

  const int D1 = 96; const int N1 = D1 * D1 * D1;
  const int D0 = 48; const int N0 = D0 * D0 * D0;

  // ---- workspace layout (~236 MB) ----
  char* wsp = (char*)d_ws;
  double* pbuf  = (double*)wsp;          wsp += (size_t)64 * 13824 * 2 * 8; // 14.2 MB
  float2* musc  = (float2*)wsp;          wsp += 1024;
  bf16* w1p     = (bf16*)wsp;            wsp += 27 * 2 * 1 * 512 * 2;  // K-packed uses 7*2*512
  bf16* w2p     = (bf16*)wsp;            wsp += 27 * 4 * 1 * 512 * 2;
  bf16* w3p     = (bf16*)wsp;            wsp += 27 * 2 * 2 * 512 * 2;
  bf16* w4p     = (bf16*)wsp;            wsp += 27 * 1 * 1 * 512 * 2;
  float* si0    = (float*)wsp;           wsp += (size_t)N0 * 4;
  float* smov0  = (float*)wsp;           wsp += (size_t)N0 * 4;
  float* vf0    = (float*)wsp;           wsp += 3 * (size_t)N1 * 4;
  float* vf1    = (float*)wsp;           wsp += 3 * (size_t)N1 * 4;
  bf16* feat    = (bf16*)wsp;            wsp += 8 * (size_t)N1 * 2;
  bf16* bufA    = (bf16*)wsp;            wsp += 32 * (size_t)N1 * 2;
  bf16* bufB    = (bf16*)wsp;            wsp += 64 * (size_t)N1 * 2;

  // ---- weight packing (bf16, fragment order; conv1 K-packed) ----
  pack_w1p_k<<<(7 * 2 * 512 + 255) / 256, 256, 0, stream>>>(w1, w1p);
  pack_wf_k<<<(27 * 4 * 512 + 255) / 256, 256, 0, stream>>>(w2, w2p, 4, 1, 64, 32);
  pack_wf_k<<<(27 * 4 * 512 + 255) / 256, 256, 0, stream>>>(w3, w3p, 2, 2, 32, 64);
  pack_wf_k<<<(27 * 1 * 512 + 255) / 256, 256, 0, stream>>>(w4, w4p, 1, 1, 3, 32);

  // ---- level 0 setup ----
  down2x_k<<<N0 / 256, 256, 0, stream>>>(image, si0, D0, D0, D0);
  down2x_k<<<N0 / 256, 256, 0, stream>>>(moving, smov0, D0, D0, D0);
  zero_k<<<3 * N0 / 256, 256, 0, stream>>>(vf0, 3 * N0);

  float* vfc = vf0;
  float* vfa = vf1;

  auto run_level = [&](const float* si, const float* smov, int Dd) {
    const int N = Dd * Dd * Dd;
    const int nb = N / 256;
    const dim3 gw(Dd / 8, Dd / 8, Dd / 4);    // warpforce tile 8x8x4
    const dim3 g1(Dd / 16, Dd / 4, Dd / 4);   // conv1/conv2/conv4: 16x4x4
    const dim3 g3(Dd / 16, Dd / 4, Dd / 2);   // conv3: 16x4x2
    const int G1 = g1.x * g1.y * g1.z;
    const int G3 = g3.x * g3.y * g3.z;
    for (int it = 0; it < 2; ++it) {
      warpforce_k<<<gw, 256, 0, stream>>>(smov, vfc, si, feat, Dd, Dd, Dd);

      conv1p_k<4, 4><<<g1, 512, 0, stream>>>(feat, w1p, bufA, pbuf, Dd, Dd, Dd);
      stage2_k<<<32, 256, 0, stream>>>(pbuf, musc, N, G1);
      inorm_vc_k<32><<<N / 64, 256, 0, stream>>>(bufA, musc, N);

      convmf_k<32, 64, 4, 4, 32, 1><<<g1, 512, 0, stream>>>(bufA, w2p, bufB, pbuf, Dd, Dd, Dd);
      stage2_k<<<64, 256, 0, stream>>>(pbuf, musc, N, G1);
      inorm_vc_k<64><<<N / 32, 256, 0, stream>>>(bufB, musc, N);

      convmf_k<64, 32, 2, 4, 64, 1><<<g3, 512, 0, stream>>>(bufB, w3p, bufA, pbuf, Dd, Dd, Dd);
      stage2_k<<<32, 256, 0, stream>>>(pbuf, musc, N, G3);
      inorm_vc_k<32><<<N / 64, 256, 0, stream>>>(bufA, musc, N);

      conv4mf_k<4, 4><<<g1, 512, 0, stream>>>(bufA, w4p, b4, vfc, Dd, Dd, Dd);

      smooth_k<0><<<dim3(nb, 3), 256, 0, stream>>>(vfc, vfa, Dd, Dd, Dd);
      smooth_k<1><<<dim3(nb, 3), 256, 0, stream>>>(vfa, vfc, Dd, Dd, Dd);
      smooth_k<2><<<dim3(nb, 3), 256, 0, stream>>>(vfc, vfa, Dd, Dd, Dd);
      { float* tmp = vfc; vfc = vfa; vfa = tmp; }
    }
  };

  // ---- level 0 (48^3) ----
  run_level(si0, smov0, D0);

  // ---- upsample vf to 96^3, scale displacements by 2 ----
  up2x_vf_k<<<dim3(N1 / 256, 3), 256, 0, stream>>>(vfc, vfa, D1, D1, D1);
  { float* tmp = vfc; vfc = vfa; vfa = tmp; }

  // ---- level 1 (96^3) ----
  run_level(image, moving, D1);

  // ---- outputs: warped_full, vf ----
  warp_k<<<N1 / 256, 256, 0, stream>>>(moving, vfc, out, D1, D1, D1);
  copy_k<<<3 * N1 / 256, 256, 0, stream>>>(vfc, out + N1, 3 * N1);
}

// Round 18
// 1256.980 us; speedup vs baseline: 1.3749x; 1.0115x over previous
//
#include <hip/hip_runtime.h>
#include <hip/hip_bf16.h>

// ---------------------------------------------------------------------------
// TrainableVarRegBlock: 2-level demons registration (48^3, 96^3), 2 iters each.
// R11-proven conv path: bf16 MFMA 16x16x32, 4Mx2N waves, fragment-ordered B,
// fused IN stage-1 reduce in conv epilogue, separate BW-bound inorm+fast-mish.
// LDS uses PADDED rows (CIN+8 shorts) instead of XOR swizzle -> all ds_read
// addresses are base + compile-time immediate. Chunk offset = kg*8 + kb*32.
// conv1 uses 4-taps-per-MFMA K-packing. warp+forces fused. Force path f32.
// ---------------------------------------------------------------------------

#define DEV __device__ __forceinline__
typedef __hip_bfloat16 bf16;
typedef __attribute__((ext_vector_type(8))) short short8;
typedef __attribute__((ext_vector_type(4))) float f32x4;

DEV float bfu(unsigned int u) {           // bf16 bits -> f32 (exact)
  union { unsigned int i; float f; } x; x.i = u << 16; return x.f;
}
DEV unsigned short fbf(float f) {         // f32 -> bf16 bits (RNE)
  __hip_bfloat16 h = __float2bfloat16(f);
  return __builtin_bit_cast(unsigned short, h);
}

// fast mish: x*tanh(softplus(x)) == x*(u^2+2u)/(u^2+2u+2), u=e^x (exact algebra)
DEV float mishf(float v) {
  if (v > 20.f) return v;
  float u = __expf(v);
  float w = u * (u + 2.f);
  return v * (w / (w + 2.f));
}

// ---------------- small utility kernels ----------------
__global__ void zero_k(float* __restrict__ p, int n) {
  int i = blockIdx.x * 256 + threadIdx.x;
  if (i < n) p[i] = 0.f;
}
__global__ void copy_k(const float* __restrict__ in, float* __restrict__ out, int n) {
  int i = blockIdx.x * 256 + threadIdx.x;
  if (i < n) out[i] = in[i];
}

// 16x16 fragment pack: dst[((off*NWT+nwt)*KB+kb)*512 + lane*8 + j]
// = w[co = nwt*16 + (lane&15)][ci = (kb*4 + (lane>>4))*8 + j]  (zero-padded)
__global__ void pack_wf_k(const float* __restrict__ w, bf16* __restrict__ dst,
                          int NWT, int KB, int COR, int CIR) {
  int idx = blockIdx.x * 256 + threadIdx.x;
  int tot = 27 * NWT * KB * 512;
  if (idx >= tot) return;
  int j = idx & 7;
  int lane = (idx >> 3) & 63;
  int frag = idx >> 9;
  int kb = frag % KB;
  int r2 = frag / KB;
  int nwt = r2 % NWT;
  int off = r2 / NWT;
  int co = nwt * 16 + (lane & 15);
  int ci = (kb * 4 + (lane >> 4)) * 8 + j;
  float v = (co < COR && ci < CIR) ? w[((size_t)co * CIR + ci) * 27 + off] : 0.f;
  dst[idx] = __float2bfloat16(v);
}

// conv1 4-tap K-packed weights: dst[(rd*2+nw)*512 + lane*8 + j]
// = w1[co = nw*16 + (lane&15)][ci = j][tap = rd*4 + (lane>>4)]  (zero-padded)
__global__ void pack_w1p_k(const float* __restrict__ w, bf16* __restrict__ dst) {
  int idx = blockIdx.x * 256 + threadIdx.x;
  if (idx >= 7 * 2 * 512) return;
  int j = idx & 7;
  int lane = (idx >> 3) & 63;
  int frag = idx >> 9;
  int nw = frag & 1;
  int rd = frag >> 1;
  int co = nw * 16 + (lane & 15);
  int tap = rd * 4 + (lane >> 4);
  float v = (tap < 27 && j < 5) ? w[((size_t)co * 5 + j) * 27 + tap] : 0.f;
  dst[idx] = __float2bfloat16(v);
}

// ---------------- resize helpers ----------------
DEV int ds_taps(int i, int n_out, int* j0, float* w) {
  if (i == 0) { *j0 = 0; w[0] = 3.f/7.f; w[1] = 3.f/7.f; w[2] = 1.f/7.f; return 3; }
  if (i == n_out - 1) { *j0 = 2*i - 1; w[0] = 1.f/7.f; w[1] = 3.f/7.f; w[2] = 3.f/7.f; return 3; }
  *j0 = 2*i - 1; w[0] = 0.125f; w[1] = 0.375f; w[2] = 0.375f; w[3] = 0.125f; return 4;
}
DEV void up_taps(int i, int n_in, int* j0, int* j1, float* w0, float* w1) {
  if (i & 1) {
    int k = i >> 1;
    if (k + 1 >= n_in) { *j0 = n_in - 1; *j1 = n_in - 1; *w0 = 1.f; *w1 = 0.f; }
    else { *j0 = k; *j1 = k + 1; *w0 = 0.75f; *w1 = 0.25f; }
  } else {
    int k = i >> 1;
    if (k == 0) { *j0 = 0; *j1 = 0; *w0 = 1.f; *w1 = 0.f; }
    else { *j0 = k - 1; *j1 = k; *w0 = 0.25f; *w1 = 0.75f; }
  }
}

__global__ void down2x_k(const float* __restrict__ in, float* __restrict__ out,
                         int Do, int Ho, int Wo) {
  const int Hi = 2 * Ho, Wi = 2 * Wo;
  const int No = Do * Ho * Wo;
  int i = blockIdx.x * 256 + threadIdx.x;
  if (i >= No) return;
  int xo = i % Wo; int t = i / Wo; int yo = t % Ho; int zo = t / Ho;
  int jz0, jy0, jx0; float wz[4], wy[4], wx[4];
  int cz = ds_taps(zo, Do, &jz0, wz);
  int cy = ds_taps(yo, Ho, &jy0, wy);
  int cx = ds_taps(xo, Wo, &jx0, wx);
  float s = 0.f;
  for (int a = 0; a < cz; ++a) {
    const float* pz = in + (size_t)(jz0 + a) * Hi * Wi;
    for (int b = 0; b < cy; ++b) {
      const float* py = pz + (size_t)(jy0 + b) * Wi;
      float wab = wz[a] * wy[b];
      for (int d = 0; d < cx; ++d) s += wab * wx[d] * py[jx0 + d];
    }
  }
  out[i] = s;
}

__global__ void up2x_vf_k(const float* __restrict__ in, float* __restrict__ out,
                          int Do, int Ho, int Wo) {
  const int Di = Do / 2, Hi = Ho / 2, Wi = Wo / 2;
  const int No = Do * Ho * Wo;
  const int c = blockIdx.y;
  int i = blockIdx.x * 256 + threadIdx.x;
  if (i >= No) return;
  int xo = i % Wo; int t = i / Wo; int yo = t % Ho; int zo = t / Ho;
  int jz0, jz1, jy0, jy1, jx0, jx1; float wz0, wz1, wy0, wy1, wx0, wx1;
  up_taps(zo, Di, &jz0, &jz1, &wz0, &wz1);
  up_taps(yo, Hi, &jy0, &jy1, &wy0, &wy1);
  up_taps(xo, Wi, &jx0, &jx1, &wx0, &wx1);
  const float* p = in + (size_t)c * Di * Hi * Wi;
  float v00 = wx0 * p[(jz0 * Hi + jy0) * Wi + jx0] + wx1 * p[(jz0 * Hi + jy0) * Wi + jx1];
  float v01 = wx0 * p[(jz0 * Hi + jy1) * Wi + jx0] + wx1 * p[(jz0 * Hi + jy1) * Wi + jx1];
  float v10 = wx0 * p[(jz1 * Hi + jy0) * Wi + jx0] + wx1 * p[(jz1 * Hi + jy0) * Wi + jx1];
  float v11 = wx0 * p[(jz1 * Hi + jy1) * Wi + jx0] + wx1 * p[(jz1 * Hi + jy1) * Wi + jx1];
  float s = wz0 * (wy0 * v00 + wy1 * v01) + wz1 * (wy0 * v10 + wy1 * v11);
  out[(size_t)c * No + i] = 2.f * s;
}

// ---------------- warp helper (trilinear, border clamp) ----------------------
DEV float warp1(const float* __restrict__ img, const float* __restrict__ vf,
                int x, int y, int z, size_t i, int D, int H, int W, size_t N) {
  float zc = fminf(fmaxf((float)z + vf[i], 0.f), (float)(D - 1));
  float yc = fminf(fmaxf((float)y + vf[N + i], 0.f), (float)(H - 1));
  float xc = fminf(fmaxf((float)x + vf[2 * N + i], 0.f), (float)(W - 1));
  float zf = floorf(zc), yf = floorf(yc), xf = floorf(xc);
  int z0 = (int)zf, y0 = (int)yf, x0 = (int)xf;
  float wz = zc - zf, wy = yc - yf, wx = xc - xf;
  int z1 = min(z0 + 1, D - 1), y1 = min(y0 + 1, H - 1), x1 = min(x0 + 1, W - 1);
  const int HW = H * W;
  float v000 = img[z0 * HW + y0 * W + x0];
  float v001 = img[z0 * HW + y0 * W + x1];
  float v010 = img[z0 * HW + y1 * W + x0];
  float v011 = img[z0 * HW + y1 * W + x1];
  float v100 = img[z1 * HW + y0 * W + x0];
  float v101 = img[z1 * HW + y0 * W + x1];
  float v110 = img[z1 * HW + y1 * W + x0];
  float v111 = img[z1 * HW + y1 * W + x1];
  return v000 * (1 - wz) * (1 - wy) * (1 - wx)
       + v001 * (1 - wz) * (1 - wy) * wx
       + v010 * (1 - wz) * wy * (1 - wx)
       + v011 * (1 - wz) * wy * wx
       + v100 * wz * (1 - wy) * (1 - wx)
       + v101 * wz * (1 - wy) * wx
       + v110 * wz * wy * (1 - wx)
       + v111 * wz * wy * wx;
}

__global__ void warp_k(const float* __restrict__ img, const float* __restrict__ vf,
                       float* __restrict__ out, int D, int H, int W) {
  const size_t N = (size_t)D * H * W;
  size_t i = (size_t)blockIdx.x * 256 + threadIdx.x;
  if (i >= N) return;
  int x = i % W; int t = i / W; int y = t % H; int z = t / H;
  out[i] = warp1(img, vf, x, y, z, i, D, H, W, N);
}

// ---------------- fused warp + demon forces -> feat [vox][8] bf16 ------------
__global__ void __launch_bounds__(256) warpforce_k(
    const float* __restrict__ img, const float* __restrict__ vf,
    const float* __restrict__ si, bf16* __restrict__ feat, int D, int H, int W) {
  __shared__ float wt[600];
  const size_t N = (size_t)D * H * W;
  const int t = threadIdx.x;
  const int tx = t & 7, ty = (t >> 3) & 7, tz = t >> 6;
  const int gx0 = blockIdx.x * 8, gy0 = blockIdx.y * 8, gz0 = blockIdx.z * 4;
  for (int cid = t; cid < 600; cid += 256) {
    int hx = cid % 10; int r = cid / 10; int hy = r % 10; int hz = r / 10;
    int gz = gz0 + hz - 1, gy = gy0 + hy - 1, gx = gx0 + hx - 1;
    float w = 0.f;
    if (((unsigned)gz < (unsigned)D) & ((unsigned)gy < (unsigned)H) & ((unsigned)gx < (unsigned)W)) {
      size_t i = (size_t)(gz * H + gy) * W + gx;
      w = warp1(img, vf, gx, gy, gz, i, D, H, W, N);
    }
    wt[cid] = w;
  }
  __syncthreads();
  const int x = gx0 + tx, y = gy0 + ty, z = gz0 + tz;
  const size_t i = (size_t)(z * H + y) * W + x;
  const int c = (tz + 1) * 100 + (ty + 1) * 10 + (tx + 1);
  float wv = wt[c];
  float gz = (z == 0) ? (wt[c + 100] - wv) : (z == D - 1) ? (wv - wt[c - 100]) : 0.5f * (wt[c + 100] - wt[c - 100]);
  float gy = (y == 0) ? (wt[c + 10] - wv) : (y == H - 1) ? (wv - wt[c - 10]) : 0.5f * (wt[c + 10] - wt[c - 10]);
  float gx = (x == 0) ? (wt[c + 1] - wv) : (x == W - 1) ? (wv - wt[c - 1]) : 0.5f * (wt[c + 1] - wt[c - 1]);
  float s = si[i];
  float diff = wv - s;
  float denom = gz * gz + gy * gy + gx * gx + diff * diff + 1e-9f;
  short8 o;
  o[0] = (short)fbf((diff * gz) / denom);
  o[1] = (short)fbf((diff * gy) / denom);
  o[2] = (short)fbf((diff * gx) / denom);
  o[3] = (short)fbf(s);
  o[4] = (short)fbf(wv);
  o[5] = 0; o[6] = 0; o[7] = 0;
  *(short8*)((short*)feat + i * 8) = o;
}

// ---------------- conv1 K-packed: feat [vox][8] -> bufA [vox][32] raw --------
template <int TZ, int TY>
__global__ void __launch_bounds__(512) conv1p_k(
    const bf16* __restrict__ feat, const bf16* __restrict__ wpk,
    bf16* __restrict__ out, double* __restrict__ pbuf, int D, int H, int W) {
  constexpr int HZ = TZ + 2, HY = TY + 2;
  constexpr int HALO = HZ * HY * 18;
  constexpr int MS = TZ * TY / 4;
  __shared__ short lds[HALO * 8];
  __shared__ float2 red[8][1][16];
  const int t = threadIdx.x;
  const int gx0 = blockIdx.x * 16, gy0 = blockIdx.y * TY, gz0 = blockIdx.z * TZ;
  const short* featS = (const short*)feat;
  for (int pos = t; pos < HALO; pos += 512) {
    int hx = pos % 18; int r = pos / 18; int hy = r % HY; int hz = r / HY;
    int gz = gz0 + hz - 1, gy = gy0 + hy - 1, gx = gx0 + hx - 1;
    uint4 v = {0u, 0u, 0u, 0u};
    if (((unsigned)gz < (unsigned)D) & ((unsigned)gy < (unsigned)H) & ((unsigned)gx < (unsigned)W))
      v = *(const uint4*)(featS + ((size_t)(gz * H + gy) * W + gx) * 8);
    *(uint4*)(lds + pos * 8) = v;
  }
  __syncthreads();
  const int lane = t & 63, wid = t >> 6;
  const int mw = wid & 3, nw = wid >> 2;
  const int lid = lane & 15, kg = lane >> 4;
  f32x4 acc[MS];
#pragma unroll
  for (int ms = 0; ms < MS; ++ms) acc[ms] = {0.f, 0.f, 0.f, 0.f};
  int rowpos[MS];
#pragma unroll
  for (int ms = 0; ms < MS; ++ms) {
    int r = mw * MS + ms;
    rowpos[ms] = ((r / TY) * HY + (r % TY)) * 18 + lid;
  }
  const short* wp = (const short*)wpk;
#pragma unroll
  for (int rd = 0; rd < 7; ++rd) {
    int tap = rd * 4 + kg;
    int tp = tap > 26 ? 26 : tap;             // clamp for addressing (B slot zero)
    int kz = tp / 9, ky = (tp / 3) % 3, kx = tp % 3;
    int delta = (kz * HY + ky) * 18 + kx;
    short8 b = *(const short8*)(wp + ((size_t)(rd * 2 + nw) << 9) + lane * 8);
#pragma unroll
    for (int ms = 0; ms < MS; ++ms) {
      short8 a = *(const short8*)(lds + (rowpos[ms] + delta) * 8);
      acc[ms] = __builtin_amdgcn_mfma_f32_16x16x32_bf16(a, b, acc[ms], 0, 0, 0);
    }
  }
  const int xe = kg * 4;
#pragma unroll
  for (int ms = 0; ms < MS; ++ms) {
    int r = mw * MS + ms;
    int z = gz0 + r / TY, y = gy0 + r % TY;
    size_t voxb = (size_t)(z * H + y) * W + gx0;
    int co = nw * 16 + lid;
#pragma unroll
    for (int rg = 0; rg < 4; ++rg)
      out[(voxb + xe + rg) * 32 + co] = __float2bfloat16(acc[ms][rg]);
  }
  {
    float s = 0.f, q = 0.f;
#pragma unroll
    for (int ms = 0; ms < MS; ++ms)
#pragma unroll
      for (int rg = 0; rg < 4; ++rg) {
        float v = acc[ms][rg];
        s += v; q += v * v;
      }
    s += __shfl_xor(s, 16); q += __shfl_xor(q, 16);
    s += __shfl_xor(s, 32); q += __shfl_xor(q, 32);
    if (lane < 16) red[wid][0][lane] = make_float2(s, q);
    __syncthreads();
    if (t < 32) {
      const int nw_ = t >> 4, lid_ = t & 15;
      float S = 0.f, Q = 0.f;
#pragma unroll
      for (int m = 0; m < 4; ++m) {
        float2 v = red[nw_ * 4 + m][0][lid_];
        S += v.x; Q += v.y;
      }
      const int G = gridDim.x * gridDim.y * gridDim.z;
      const int bid = blockIdx.x + gridDim.x * (blockIdx.y + gridDim.y * blockIdx.z);
      pbuf[((size_t)t * G + bid) * 2 + 0] = (double)S;
      pbuf[((size_t)t * G + bid) * 2 + 1] = (double)Q;
    }
  }
}

// ---------------- MFMA 3^3 conv: 27 shifted GEMMs (R11 + padded LDS) --------
// LDS rows padded to CIN+8 shorts: read addr = base + constexpr immediate.
// Chunk c = kb*4+kg -> short offset kg*8 (base) + kb*32 (immediate).
template <int CIN, int COUT, int TZ, int TY, int INS, int REDUCE>
__global__ void __launch_bounds__(512) convmf_k(
    const bf16* __restrict__ act, const bf16* __restrict__ wpk,
    bf16* __restrict__ out, double* __restrict__ pbuf, int D, int H, int W) {
  constexpr int CH = CIN / 8;
  constexpr int RBS = CIN + 8;         // padded row stride (shorts)
  constexpr int HZ = TZ + 2, HY = TY + 2;
  constexpr int HALO = HZ * HY * 18;
  constexpr int MS = TZ * TY / 4;
  constexpr int NS = COUT / 32;
  constexpr int NWT = COUT / 16;
  constexpr int KB = CIN / 32;
  __shared__ short lds[HALO * RBS];
  __shared__ float2 red[8][NS][16];
  const int t = threadIdx.x;
  const int gx0 = blockIdx.x * 16, gy0 = blockIdx.y * TY, gz0 = blockIdx.z * TZ;
  const short* actS = (const short*)act;
  for (int cid = t; cid < HALO * CH; cid += 512) {
    int pos = cid / CH, c = cid - pos * CH;
    int hx = pos % 18; int r = pos / 18; int hy = r % HY; int hz = r / HY;
    int gz = gz0 + hz - 1, gy = gy0 + hy - 1, gx = gx0 + hx - 1;
    uint4 v = {0u, 0u, 0u, 0u};
    if (((unsigned)gz < (unsigned)D) & ((unsigned)gy < (unsigned)H) & ((unsigned)gx < (unsigned)W)) {
      size_t vox = (size_t)(gz * H + gy) * W + gx;
      if (INS == 8) { if (c == 0) v = *(const uint4*)(actS + vox * 8); }
      else v = *(const uint4*)(actS + vox * CIN + c * 8);
    }
    *(uint4*)(lds + pos * RBS + c * 8) = v;
  }
  __syncthreads();
  const int lane = t & 63, wid = t >> 6;
  const int mw = wid & 3, nw = wid >> 2;
  const int lid = lane & 15, kg = lane >> 4;
  f32x4 acc[MS][NS];
#pragma unroll
  for (int ms = 0; ms < MS; ++ms)
#pragma unroll
    for (int n = 0; n < NS; ++n) acc[ms][n] = {0.f, 0.f, 0.f, 0.f};
  int rowbase[MS];                     // LDS short-offset base per M-subtile
#pragma unroll
  for (int ms = 0; ms < MS; ++ms) {
    int r = mw * MS + ms;
    rowbase[ms] = (((r / TY) * HY + (r % TY)) * 18 + lid) * RBS + kg * 8;
  }
  const short* wp = (const short*)wpk;
#pragma unroll 1
  for (int kz = 0; kz < 3; ++kz)
#pragma unroll 1
    for (int ky = 0; ky < 3; ++ky) {
      const int dbase = ((kz * HY + ky) * 18) * RBS;
#pragma unroll
      for (int kx = 0; kx < 3; ++kx) {
        const int off = (kz * 3 + ky) * 3 + kx;
        short8 bq[NS][KB];
#pragma unroll
        for (int n = 0; n < NS; ++n)
#pragma unroll
          for (int kb = 0; kb < KB; ++kb)
            bq[n][kb] = *(const short8*)(wp + ((((size_t)off * NWT + nw * NS + n) * KB + kb) << 9) + lane * 8);
#pragma unroll
        for (int ms = 0; ms < MS; ++ms) {
#pragma unroll
          for (int kb = 0; kb < KB; ++kb) {
            short8 a = *(const short8*)(lds + rowbase[ms] + dbase + kx * RBS + kb * 32);
#pragma unroll
            for (int n = 0; n < NS; ++n)
              acc[ms][n] = __builtin_amdgcn_mfma_f32_16x16x32_bf16(a, bq[n][kb], acc[ms][n], 0, 0, 0);
          }
        }
      }
    }
  const int xe = kg * 4;
#pragma unroll
  for (int ms = 0; ms < MS; ++ms) {
    int r = mw * MS + ms;
    int z = gz0 + r / TY, y = gy0 + r % TY;
    size_t voxb = (size_t)(z * H + y) * W + gx0;
#pragma unroll
    for (int n = 0; n < NS; ++n) {
      int co = nw * NS * 16 + n * 16 + lid;
#pragma unroll
      for (int rg = 0; rg < 4; ++rg)
        out[(voxb + xe + rg) * COUT + co] = __float2bfloat16(acc[ms][n][rg]);
    }
  }
  if (REDUCE) {
#pragma unroll
    for (int n = 0; n < NS; ++n) {
      float s = 0.f, q = 0.f;
#pragma unroll
      for (int ms = 0; ms < MS; ++ms)
#pragma unroll
        for (int rg = 0; rg < 4; ++rg) {
          float v = acc[ms][n][rg];
          s += v; q += v * v;
        }
      s += __shfl_xor(s, 16); q += __shfl_xor(q, 16);
      s += __shfl_xor(s, 32); q += __shfl_xor(q, 32);
      if (lane < 16) red[wid][n][lane] = make_float2(s, q);
    }
    __syncthreads();
    if (t < COUT) {
      const int nw_ = t / (NS * 16);
      const int rem = t - nw_ * NS * 16;
      const int n_ = rem >> 4, lid_ = rem & 15;
      float S = 0.f, Q = 0.f;
#pragma unroll
      for (int m = 0; m < 4; ++m) {
        float2 v = red[nw_ * 4 + m][n_][lid_];
        S += v.x; Q += v.y;
      }
      const int G = gridDim.x * gridDim.y * gridDim.z;
      const int bid = blockIdx.x + gridDim.x * (blockIdx.y + gridDim.y * blockIdx.z);
      pbuf[((size_t)t * G + bid) * 2 + 0] = (double)S;
      pbuf[((size_t)t * G + bid) * 2 + 1] = (double)Q;
    }
  }
}

// ---------------- conv4 MFMA 16x16x32 (padded LDS): bufA -> vf f32 [3][N] ----
template <int TZ, int TY>
__global__ void __launch_bounds__(512) conv4mf_k(
    const bf16* __restrict__ act, const bf16* __restrict__ wpk,
    const float* __restrict__ bias, float* __restrict__ vf, int D, int H, int W) {
  constexpr int CH = 4;
  constexpr int RBS = 40;              // 32 + 8 padded row stride
  constexpr int HZ = TZ + 2, HY = TY + 2;
  constexpr int HALO = HZ * HY * 18;
  constexpr int MS = TZ * TY / 8;
  __shared__ short lds[HALO * RBS];
  const int t = threadIdx.x;
  const int gx0 = blockIdx.x * 16, gy0 = blockIdx.y * TY, gz0 = blockIdx.z * TZ;
  const int N = D * H * W;
  const short* actS = (const short*)act;
  for (int cid = t; cid < HALO * CH; cid += 512) {
    int pos = cid / CH, c = cid - pos * CH;
    int hx = pos % 18; int r = pos / 18; int hy = r % HY; int hz = r / HY;
    int gz = gz0 + hz - 1, gy = gy0 + hy - 1, gx = gx0 + hx - 1;
    uint4 v = {0u, 0u, 0u, 0u};
    if (((unsigned)gz < (unsigned)D) & ((unsigned)gy < (unsigned)H) & ((unsigned)gx < (unsigned)W))
      v = *(const uint4*)(actS + ((size_t)(gz * H + gy) * W + gx) * 32 + c * 8);
    *(uint4*)(lds + pos * RBS + c * 8) = v;
  }
  __syncthreads();
  const int lane = t & 63, wid = t >> 6;
  const int lid = lane & 15, kg = lane >> 4;
  f32x4 acc[MS];
#pragma unroll
  for (int ms = 0; ms < MS; ++ms) acc[ms] = {0.f, 0.f, 0.f, 0.f};
  int rowbase[MS];
#pragma unroll
  for (int ms = 0; ms < MS; ++ms) {
    int r = wid * MS + ms;
    rowbase[ms] = (((r / TY) * HY + (r % TY)) * 18 + lid) * RBS + kg * 8;
  }
  const short* wp = (const short*)wpk;
#pragma unroll 1
  for (int kz = 0; kz < 3; ++kz)
#pragma unroll 1
    for (int ky = 0; ky < 3; ++ky) {
      const int dbase = ((kz * HY + ky) * 18) * RBS;
#pragma unroll
      for (int kx = 0; kx < 3; ++kx) {
        const int off = (kz * 3 + ky) * 3 + kx;
        short8 b = *(const short8*)(wp + ((size_t)off << 9) + lane * 8);
#pragma unroll
        for (int ms = 0; ms < MS; ++ms) {
          short8 a = *(const short8*)(lds + rowbase[ms] + dbase + kx * RBS);
          acc[ms] = __builtin_amdgcn_mfma_f32_16x16x32_bf16(a, b, acc[ms], 0, 0, 0);
        }
      }
    }
  if (lid < 3) {
    float bs = bias[lid];
#pragma unroll
    for (int ms = 0; ms < MS; ++ms) {
      int r = wid * MS + ms;
      int z = gz0 + r / TY, y = gy0 + r % TY;
      size_t voxb = (size_t)(z * H + y) * W + gx0 + kg * 4;
      float* p = vf + (size_t)lid * N + voxb;
#pragma unroll
      for (int rg = 0; rg < 4; ++rg) p[rg] += acc[ms][rg] + bs;
    }
  }
}

// ---------------- InstanceNorm stage-2 (musc = mean, inv-std) ----------------
__global__ void stage2_k(const double* __restrict__ pbuf, float2* __restrict__ musc,
                         int N, int G) {
  const int c = blockIdx.x;
  double S = 0, Q = 0;
  for (int g = threadIdx.x; g < G; g += 256) {
    S += pbuf[((size_t)c * G + g) * 2 + 0];
    Q += pbuf[((size_t)c * G + g) * 2 + 1];
  }
  for (int off = 32; off > 0; off >>= 1) {
    S += __shfl_down(S, off); Q += __shfl_down(Q, off);
  }
  __shared__ double ls[4], lq[4];
  const int wid = threadIdx.x >> 6, lane = threadIdx.x & 63;
  if (lane == 0) { ls[wid] = S; lq[wid] = Q; }
  __syncthreads();
  if (threadIdx.x == 0) {
    double St = ls[0] + ls[1] + ls[2] + ls[3];
    double Qt = lq[0] + lq[1] + lq[2] + lq[3];
    double m = St / N;
    double var = Qt / N - m * m;
    musc[c] = make_float2((float)m, (float)(1.0 / sqrt(var + 1e-5)));
  }
}

template <int C>
__global__ void inorm_vc_k(bf16* __restrict__ x, const float2* __restrict__ musc, int N) {
  constexpr int CP = C / 2;
  constexpr int VPB = 256 / CP;
  const int cp = threadIdx.x & (CP - 1);
  const int vt = threadIdx.x / CP;
  float2 m0 = musc[2 * cp], m1 = musc[2 * cp + 1];
  unsigned int* p = (unsigned int*)x;
  int v0 = blockIdx.x * (4 * VPB) + vt;
#pragma unroll
  for (int r = 0; r < 4; ++r) {
    int v = v0 + r * VPB;
    size_t idx = (size_t)v * CP + cp;
    unsigned int u = p[idx];
    float a = mishf((bfu(u & 0xffffu) - m0.x) * m0.y);
    float b = mishf((bfu(u >> 16) - m1.x) * m1.y);
    p[idx] = (unsigned int)fbf(a) | ((unsigned int)fbf(b) << 16);
  }
}

// ---------------- separable 7-tap Gaussian, zero padded ----------------------
template <int AXIS>
__global__ void smooth_k(const float* __restrict__ in, float* __restrict__ out,
                         int D, int H, int W) {
  const int N = D * H * W;
  const int c = blockIdx.y;
  int i = blockIdx.x * 256 + threadIdx.x;
  if (i >= N) return;
  int x = i % W; int t = i / W; int y = t % H; int z = t / H;
  const int coord = AXIS == 0 ? z : AXIS == 1 ? y : x;
  const int len = AXIS == 0 ? D : AXIS == 1 ? H : W;
  const int stride = AXIS == 0 ? H * W : AXIS == 1 ? W : 1;
  const float k1 = 0.60653065971263342f, k2 = 0.13533528323661270f, k3 = 0.011108996538242306f;
  const float kn = 1.f / (1.f + 2.f * (k1 + k2 + k3));
  const float gw[4] = {kn, k1 * kn, k2 * kn, k3 * kn};
  const float* p = in + (size_t)c * N;
  float s = gw[0] * p[i];
#pragma unroll
  for (int tt = 1; tt <= 3; ++tt) {
    if (coord - tt >= 0) s += gw[tt] * p[i - tt * stride];
    if (coord + tt < len) s += gw[tt] * p[i + tt * stride];
  }
  out[(size_t)c * N + i] = s;
}

// ---------------------------------------------------------------------------
extern "C" void kernel_launch(void* const* d_in, const int* in_sizes, int n_in,
                              void* d_out, int out_size, void* d_ws, size_t ws_size,
                              hipStream_t stream) {
  const float* image  = (const float*)d_in[0];
  const float* moving = (const float*)d_in[2];
  const float* w1 = (const float*)d_in[4];
  const float* w2 = (const float*)d_in[5];
  const float* w3 = (const float*)d_in[6];
  const float* w4 = (const float*)d_in[7];
  const float* b4 = (const float*)d_in[8];
  float* out = (float*)d_out;

  const int D1 = 96; const int N1 = D1 * D1 * D1;
  const int D0 = 48; const int N0 = D0 * D0 * D0;

  // ---- workspace layout (~236 MB) ----
  char* wsp = (char*)d_ws;
  double* pbuf  = (double*)wsp;          wsp += (size_t)64 * 13824 * 2 * 8; // 14.2 MB
  float2* musc  = (float2*)wsp;          wsp += 1024;
  bf16* w1p     = (bf16*)wsp;            wsp += 27 * 2 * 1 * 512 * 2;  // K-packed uses 7*2*512
  bf16* w2p     = (bf16*)wsp;            wsp += 27 * 4 * 1 * 512 * 2;
  bf16* w3p     = (bf16*)wsp;            wsp += 27 * 2 * 2 * 512 * 2;
  bf16* w4p     = (bf16*)wsp;            wsp += 27 * 1 * 1 * 512 * 2;
  float* si0    = (float*)wsp;           wsp += (size_t)N0 * 4;
  float* smov0  = (float*)wsp;           wsp += (size_t)N0 * 4;
  float* vf0    = (float*)wsp;           wsp += 3 * (size_t)N1 * 4;
  float* vf1    = (float*)wsp;           wsp += 3 * (size_t)N1 * 4;
  bf16* feat    = (bf16*)wsp;            wsp += 8 * (size_t)N1 * 2;
  bf16* bufA    = (bf16*)wsp;            wsp += 32 * (size_t)N1 * 2;
  bf16* bufB    = (bf16*)wsp;            wsp += 64 * (size_t)N1 * 2;

  // ---- weight packing (bf16, fragment order; conv1 K-packed) ----
  pack_w1p_k<<<(7 * 2 * 512 + 255) / 256, 256, 0, stream>>>(w1, w1p);
  pack_wf_k<<<(27 * 4 * 512 + 255) / 256, 256, 0, stream>>>(w2, w2p, 4, 1, 64, 32);
  pack_wf_k<<<(27 * 4 * 512 + 255) / 256, 256, 0, stream>>>(w3, w3p, 2, 2, 32, 64);
  pack_wf_k<<<(27 * 1 * 512 + 255) / 256, 256, 0, stream>>>(w4, w4p, 1, 1, 3, 32);

  // ---- level 0 setup ----
  down2x_k<<<N0 / 256, 256, 0, stream>>>(image, si0, D0, D0, D0);
  down2x_k<<<N0 / 256, 256, 0, stream>>>(moving, smov0, D0, D0, D0);
  zero_k<<<3 * N0 / 256, 256, 0, stream>>>(vf0, 3 * N0);

  float* vfc = vf0;
  float* vfa = vf1;

  auto run_level = [&](const float* si, const float* smov, int Dd) {
    const int N = Dd * Dd * Dd;
    const int nb = N / 256;
    const dim3 gw(Dd / 8, Dd / 8, Dd / 4);    // warpforce tile 8x8x4
    const dim3 g1(Dd / 16, Dd / 4, Dd / 4);   // conv1/conv2/conv4: 16x4x4
    const dim3 g3(Dd / 16, Dd / 4, Dd / 2);   // conv3: 16x4x2
    const int G1 = g1.x * g1.y * g1.z;
    const int G3 = g3.x * g3.y * g3.z;
    for (int it = 0; it < 2; ++it) {
      warpforce_k<<<gw, 256, 0, stream>>>(smov, vfc, si, feat, Dd, Dd, Dd);

      conv1p_k<4, 4><<<g1, 512, 0, stream>>>(feat, w1p, bufA, pbuf, Dd, Dd, Dd);
      stage2_k<<<32, 256, 0, stream>>>(pbuf, musc, N, G1);
      inorm_vc_k<32><<<N / 64, 256, 0, stream>>>(bufA, musc, N);

      convmf_k<32, 64, 4, 4, 32, 1><<<g1, 512, 0, stream>>>(bufA, w2p, bufB, pbuf, Dd, Dd, Dd);
      stage2_k<<<64, 256, 0, stream>>>(pbuf, musc, N, G1);
      inorm_vc_k<64><<<N / 32, 256, 0, stream>>>(bufB, musc, N);

      convmf_k<64, 32, 2, 4, 64, 1><<<g3, 512, 0, stream>>>(bufB, w3p, bufA, pbuf, Dd, Dd, Dd);
      stage2_k<<<32, 256, 0, stream>>>(pbuf, musc, N, G3);
      inorm_vc_k<32><<<N / 64, 256, 0, stream>>>(bufA, musc, N);

      conv4mf_k<4, 4><<<g1, 512, 0, stream>>>(bufA, w4p, b4, vfc, Dd, Dd, Dd);

      smooth_k<0><<<dim3(nb, 3), 256, 0, stream>>>(vfc, vfa, Dd, Dd, Dd);
      smooth_k<1><<<dim3(nb, 3), 256, 0, stream>>>(vfa, vfc, Dd, Dd, Dd);
      smooth_k<2><<<dim3(nb, 3), 256, 0, stream>>>(vfc, vfa, Dd, Dd, Dd);
      { float* tmp = vfc; vfc = vfa; vfa = tmp; }
    }
  };

  // ---- level 0 (48^3) ----
  run_level(si0, smov0, D0);

  // ---- upsample vf to 96^3, scale displacements by 2 ----
  up2x_vf_k<<<dim3(N1 / 256, 3), 256, 0, stream>>>(vfc, vfa, D1, D1, D1);
  { float* tmp = vfc; vfc = vfa; vfa = tmp; }

  // ---- level 1 (96^3) ----
  run_level(image, moving, D1);

  // ---- outputs: warped_full, vf ----
  warp_k<<<N1 / 256, 256, 0, stream>>>(moving, vfc, out, D1, D1, D1);
  copy_k<<<3 * N1 / 256, 256, 0, stream>>>(vfc, out + N1, 3 * N1);
}

// Round 19
// 1205.964 us; speedup vs baseline: 1.4330x; 1.0423x over previous
//
#include <hip/hip_runtime.h>
#include <hip/hip_bf16.h>

// ---------------------------------------------------------------------------
// TrainableVarRegBlock: 2-level demons registration (48^3, 96^3), 2 iters each.
// R18 conv path (padded-LDS MFMA 16x16x32, fragment B, fused IN stage-1,
// conv1 K-packed, fast mish, warpforce fused). This round: 3 smooth axes
// fused into one kernel (LDS 14^3 halo, bit-identical op order), final
// smooth writes directly into d_out (+N1) eliminating the vf copy.
// ---------------------------------------------------------------------------

#define DEV __device__ __forceinline__
typedef __hip_bfloat16 bf16;
typedef __attribute__((ext_vector_type(8))) short short8;
typedef __attribute__((ext_vector_type(4))) float f32x4;

DEV float bfu(unsigned int u) {           // bf16 bits -> f32 (exact)
  union { unsigned int i; float f; } x; x.i = u << 16; return x.f;
}
DEV unsigned short fbf(float f) {         // f32 -> bf16 bits (RNE)
  __hip_bfloat16 h = __float2bfloat16(f);
  return __builtin_bit_cast(unsigned short, h);
}

// fast mish: x*tanh(softplus(x)) == x*(u^2+2u)/(u^2+2u+2), u=e^x (exact algebra)
DEV float mishf(float v) {
  if (v > 20.f) return v;
  float u = __expf(v);
  float w = u * (u + 2.f);
  return v * (w / (w + 2.f));
}

// ---------------- small utility kernels ----------------
__global__ void zero_k(float* __restrict__ p, int n) {
  int i = blockIdx.x * 256 + threadIdx.x;
  if (i < n) p[i] = 0.f;
}

// 16x16 fragment pack: dst[((off*NWT+nwt)*KB+kb)*512 + lane*8 + j]
// = w[co = nwt*16 + (lane&15)][ci = (kb*4 + (lane>>4))*8 + j]  (zero-padded)
__global__ void pack_wf_k(const float* __restrict__ w, bf16* __restrict__ dst,
                          int NWT, int KB, int COR, int CIR) {
  int idx = blockIdx.x * 256 + threadIdx.x;
  int tot = 27 * NWT * KB * 512;
  if (idx >= tot) return;
  int j = idx & 7;
  int lane = (idx >> 3) & 63;
  int frag = idx >> 9;
  int kb = frag % KB;
  int r2 = frag / KB;
  int nwt = r2 % NWT;
  int off = r2 / NWT;
  int co = nwt * 16 + (lane & 15);
  int ci = (kb * 4 + (lane >> 4)) * 8 + j;
  float v = (co < COR && ci < CIR) ? w[((size_t)co * CIR + ci) * 27 + off] : 0.f;
  dst[idx] = __float2bfloat16(v);
}

// conv1 4-tap K-packed weights: dst[(rd*2+nw)*512 + lane*8 + j]
// = w1[co = nw*16 + (lane&15)][ci = j][tap = rd*4 + (lane>>4)]  (zero-padded)
__global__ void pack_w1p_k(const float* __restrict__ w, bf16* __restrict__ dst) {
  int idx = blockIdx.x * 256 + threadIdx.x;
  if (idx >= 7 * 2 * 512) return;
  int j = idx & 7;
  int lane = (idx >> 3) & 63;
  int frag = idx >> 9;
  int nw = frag & 1;
  int rd = frag >> 1;
  int co = nw * 16 + (lane & 15);
  int tap = rd * 4 + (lane >> 4);
  float v = (tap < 27 && j < 5) ? w[((size_t)co * 5 + j) * 27 + tap] : 0.f;
  dst[idx] = __float2bfloat16(v);
}

// ---------------- resize helpers ----------------
DEV int ds_taps(int i, int n_out, int* j0, float* w) {
  if (i == 0) { *j0 = 0; w[0] = 3.f/7.f; w[1] = 3.f/7.f; w[2] = 1.f/7.f; return 3; }
  if (i == n_out - 1) { *j0 = 2*i - 1; w[0] = 1.f/7.f; w[1] = 3.f/7.f; w[2] = 3.f/7.f; return 3; }
  *j0 = 2*i - 1; w[0] = 0.125f; w[1] = 0.375f; w[2] = 0.375f; w[3] = 0.125f; return 4;
}
DEV void up_taps(int i, int n_in, int* j0, int* j1, float* w0, float* w1) {
  if (i & 1) {
    int k = i >> 1;
    if (k + 1 >= n_in) { *j0 = n_in - 1; *j1 = n_in - 1; *w0 = 1.f; *w1 = 0.f; }
    else { *j0 = k; *j1 = k + 1; *w0 = 0.75f; *w1 = 0.25f; }
  } else {
    int k = i >> 1;
    if (k == 0) { *j0 = 0; *j1 = 0; *w0 = 1.f; *w1 = 0.f; }
    else { *j0 = k - 1; *j1 = k; *w0 = 0.25f; *w1 = 0.75f; }
  }
}

__global__ void down2x_k(const float* __restrict__ in, float* __restrict__ out,
                         int Do, int Ho, int Wo) {
  const int Hi = 2 * Ho, Wi = 2 * Wo;
  const int No = Do * Ho * Wo;
  int i = blockIdx.x * 256 + threadIdx.x;
  if (i >= No) return;
  int xo = i % Wo; int t = i / Wo; int yo = t % Ho; int zo = t / Ho;
  int jz0, jy0, jx0; float wz[4], wy[4], wx[4];
  int cz = ds_taps(zo, Do, &jz0, wz);
  int cy = ds_taps(yo, Ho, &jy0, wy);
  int cx = ds_taps(xo, Wo, &jx0, wx);
  float s = 0.f;
  for (int a = 0; a < cz; ++a) {
    const float* pz = in + (size_t)(jz0 + a) * Hi * Wi;
    for (int b = 0; b < cy; ++b) {
      const float* py = pz + (size_t)(jy0 + b) * Wi;
      float wab = wz[a] * wy[b];
      for (int d = 0; d < cx; ++d) s += wab * wx[d] * py[jx0 + d];
    }
  }
  out[i] = s;
}

__global__ void up2x_vf_k(const float* __restrict__ in, float* __restrict__ out,
                          int Do, int Ho, int Wo) {
  const int Di = Do / 2, Hi = Ho / 2, Wi = Wo / 2;
  const int No = Do * Ho * Wo;
  const int c = blockIdx.y;
  int i = blockIdx.x * 256 + threadIdx.x;
  if (i >= No) return;
  int xo = i % Wo; int t = i / Wo; int yo = t % Ho; int zo = t / Ho;
  int jz0, jz1, jy0, jy1, jx0, jx1; float wz0, wz1, wy0, wy1, wx0, wx1;
  up_taps(zo, Di, &jz0, &jz1, &wz0, &wz1);
  up_taps(yo, Hi, &jy0, &jy1, &wy0, &wy1);
  up_taps(xo, Wi, &jx0, &jx1, &wx0, &wx1);
  const float* p = in + (size_t)c * Di * Hi * Wi;
  float v00 = wx0 * p[(jz0 * Hi + jy0) * Wi + jx0] + wx1 * p[(jz0 * Hi + jy0) * Wi + jx1];
  float v01 = wx0 * p[(jz0 * Hi + jy1) * Wi + jx0] + wx1 * p[(jz0 * Hi + jy1) * Wi + jx1];
  float v10 = wx0 * p[(jz1 * Hi + jy0) * Wi + jx0] + wx1 * p[(jz1 * Hi + jy0) * Wi + jx1];
  float v11 = wx0 * p[(jz1 * Hi + jy1) * Wi + jx0] + wx1 * p[(jz1 * Hi + jy1) * Wi + jx1];
  float s = wz0 * (wy0 * v00 + wy1 * v01) + wz1 * (wy0 * v10 + wy1 * v11);
  out[(size_t)c * No + i] = 2.f * s;
}

// ---------------- warp helper (trilinear, border clamp) ----------------------
DEV float warp1(const float* __restrict__ img, const float* __restrict__ vf,
                int x, int y, int z, size_t i, int D, int H, int W, size_t N) {
  float zc = fminf(fmaxf((float)z + vf[i], 0.f), (float)(D - 1));
  float yc = fminf(fmaxf((float)y + vf[N + i], 0.f), (float)(H - 1));
  float xc = fminf(fmaxf((float)x + vf[2 * N + i], 0.f), (float)(W - 1));
  float zf = floorf(zc), yf = floorf(yc), xf = floorf(xc);
  int z0 = (int)zf, y0 = (int)yf, x0 = (int)xf;
  float wz = zc - zf, wy = yc - yf, wx = xc - xf;
  int z1 = min(z0 + 1, D - 1), y1 = min(y0 + 1, H - 1), x1 = min(x0 + 1, W - 1);
  const int HW = H * W;
  float v000 = img[z0 * HW + y0 * W + x0];
  float v001 = img[z0 * HW + y0 * W + x1];
  float v010 = img[z0 * HW + y1 * W + x0];
  float v011 = img[z0 * HW + y1 * W + x1];
  float v100 = img[z1 * HW + y0 * W + x0];
  float v101 = img[z1 * HW + y0 * W + x1];
  float v110 = img[z1 * HW + y1 * W + x0];
  float v111 = img[z1 * HW + y1 * W + x1];
  return v000 * (1 - wz) * (1 - wy) * (1 - wx)
       + v001 * (1 - wz) * (1 - wy) * wx
       + v010 * (1 - wz) * wy * (1 - wx)
       + v011 * (1 - wz) * wy * wx
       + v100 * wz * (1 - wy) * (1 - wx)
       + v101 * wz * (1 - wy) * wx
       + v110 * wz * wy * (1 - wx)
       + v111 * wz * wy * wx;
}

__global__ void warp_k(const float* __restrict__ img, const float* __restrict__ vf,
                       float* __restrict__ out, int D, int H, int W) {
  const size_t N = (size_t)D * H * W;
  size_t i = (size_t)blockIdx.x * 256 + threadIdx.x;
  if (i >= N) return;
  int x = i % W; int t = i / W; int y = t % H; int z = t / H;
  out[i] = warp1(img, vf, x, y, z, i, D, H, W, N);
}

// ---------------- fused warp + demon forces -> feat [vox][8] bf16 ------------
__global__ void __launch_bounds__(256) warpforce_k(
    const float* __restrict__ img, const float* __restrict__ vf,
    const float* __restrict__ si, bf16* __restrict__ feat, int D, int H, int W) {
  __shared__ float wt[600];
  const size_t N = (size_t)D * H * W;
  const int t = threadIdx.x;
  const int tx = t & 7, ty = (t >> 3) & 7, tz = t >> 6;
  const int gx0 = blockIdx.x * 8, gy0 = blockIdx.y * 8, gz0 = blockIdx.z * 4;
  for (int cid = t; cid < 600; cid += 256) {
    int hx = cid % 10; int r = cid / 10; int hy = r % 10; int hz = r / 10;
    int gz = gz0 + hz - 1, gy = gy0 + hy - 1, gx = gx0 + hx - 1;
    float w = 0.f;
    if (((unsigned)gz < (unsigned)D) & ((unsigned)gy < (unsigned)H) & ((unsigned)gx < (unsigned)W)) {
      size_t i = (size_t)(gz * H + gy) * W + gx;
      w = warp1(img, vf, gx, gy, gz, i, D, H, W, N);
    }
    wt[cid] = w;
  }
  __syncthreads();
  const int x = gx0 + tx, y = gy0 + ty, z = gz0 + tz;
  const size_t i = (size_t)(z * H + y) * W + x;
  const int c = (tz + 1) * 100 + (ty + 1) * 10 + (tx + 1);
  float wv = wt[c];
  float gz = (z == 0) ? (wt[c + 100] - wv) : (z == D - 1) ? (wv - wt[c - 100]) : 0.5f * (wt[c + 100] - wt[c - 100]);
  float gy = (y == 0) ? (wt[c + 10] - wv) : (y == H - 1) ? (wv - wt[c - 10]) : 0.5f * (wt[c + 10] - wt[c - 10]);
  float gx = (x == 0) ? (wt[c + 1] - wv) : (x == W - 1) ? (wv - wt[c - 1]) : 0.5f * (wt[c + 1] - wt[c - 1]);
  float s = si[i];
  float diff = wv - s;
  float denom = gz * gz + gy * gy + gx * gx + diff * diff + 1e-9f;
  short8 o;
  o[0] = (short)fbf((diff * gz) / denom);
  o[1] = (short)fbf((diff * gy) / denom);
  o[2] = (short)fbf((diff * gx) / denom);
  o[3] = (short)fbf(s);
  o[4] = (short)fbf(wv);
  o[5] = 0; o[6] = 0; o[7] = 0;
  *(short8*)((short*)feat + i * 8) = o;
}

// ---------------- conv1 K-packed: feat [vox][8] -> bufA [vox][32] raw --------
template <int TZ, int TY>
__global__ void __launch_bounds__(512) conv1p_k(
    const bf16* __restrict__ feat, const bf16* __restrict__ wpk,
    bf16* __restrict__ out, double* __restrict__ pbuf, int D, int H, int W) {
  constexpr int HZ = TZ + 2, HY = TY + 2;
  constexpr int HALO = HZ * HY * 18;
  constexpr int MS = TZ * TY / 4;
  __shared__ short lds[HALO * 8];
  __shared__ float2 red[8][1][16];
  const int t = threadIdx.x;
  const int gx0 = blockIdx.x * 16, gy0 = blockIdx.y * TY, gz0 = blockIdx.z * TZ;
  const short* featS = (const short*)feat;
  for (int pos = t; pos < HALO; pos += 512) {
    int hx = pos % 18; int r = pos / 18; int hy = r % HY; int hz = r / HY;
    int gz = gz0 + hz - 1, gy = gy0 + hy - 1, gx = gx0 + hx - 1;
    uint4 v = {0u, 0u, 0u, 0u};
    if (((unsigned)gz < (unsigned)D) & ((unsigned)gy < (unsigned)H) & ((unsigned)gx < (unsigned)W))
      v = *(const uint4*)(featS + ((size_t)(gz * H + gy) * W + gx) * 8);
    *(uint4*)(lds + pos * 8) = v;
  }
  __syncthreads();
  const int lane = t & 63, wid = t >> 6;
  const int mw = wid & 3, nw = wid >> 2;
  const int lid = lane & 15, kg = lane >> 4;
  f32x4 acc[MS];
#pragma unroll
  for (int ms = 0; ms < MS; ++ms) acc[ms] = {0.f, 0.f, 0.f, 0.f};
  int rowpos[MS];
#pragma unroll
  for (int ms = 0; ms < MS; ++ms) {
    int r = mw * MS + ms;
    rowpos[ms] = ((r / TY) * HY + (r % TY)) * 18 + lid;
  }
  const short* wp = (const short*)wpk;
#pragma unroll
  for (int rd = 0; rd < 7; ++rd) {
    int tap = rd * 4 + kg;
    int tp = tap > 26 ? 26 : tap;             // clamp for addressing (B slot zero)
    int kz = tp / 9, ky = (tp / 3) % 3, kx = tp % 3;
    int delta = (kz * HY + ky) * 18 + kx;
    short8 b = *(const short8*)(wp + ((size_t)(rd * 2 + nw) << 9) + lane * 8);
#pragma unroll
    for (int ms = 0; ms < MS; ++ms) {
      short8 a = *(const short8*)(lds + (rowpos[ms] + delta) * 8);
      acc[ms] = __builtin_amdgcn_mfma_f32_16x16x32_bf16(a, b, acc[ms], 0, 0, 0);
    }
  }
  const int xe = kg * 4;
#pragma unroll
  for (int ms = 0; ms < MS; ++ms) {
    int r = mw * MS + ms;
    int z = gz0 + r / TY, y = gy0 + r % TY;
    size_t voxb = (size_t)(z * H + y) * W + gx0;
    int co = nw * 16 + lid;
#pragma unroll
    for (int rg = 0; rg < 4; ++rg)
      out[(voxb + xe + rg) * 32 + co] = __float2bfloat16(acc[ms][rg]);
  }
  {
    float s = 0.f, q = 0.f;
#pragma unroll
    for (int ms = 0; ms < MS; ++ms)
#pragma unroll
      for (int rg = 0; rg < 4; ++rg) {
        float v = acc[ms][rg];
        s += v; q += v * v;
      }
    s += __shfl_xor(s, 16); q += __shfl_xor(q, 16);
    s += __shfl_xor(s, 32); q += __shfl_xor(q, 32);
    if (lane < 16) red[wid][0][lane] = make_float2(s, q);
    __syncthreads();
    if (t < 32) {
      const int nw_ = t >> 4, lid_ = t & 15;
      float S = 0.f, Q = 0.f;
#pragma unroll
      for (int m = 0; m < 4; ++m) {
        float2 v = red[nw_ * 4 + m][0][lid_];
        S += v.x; Q += v.y;
      }
      const int G = gridDim.x * gridDim.y * gridDim.z;
      const int bid = blockIdx.x + gridDim.x * (blockIdx.y + gridDim.y * blockIdx.z);
      pbuf[((size_t)t * G + bid) * 2 + 0] = (double)S;
      pbuf[((size_t)t * G + bid) * 2 + 1] = (double)Q;
    }
  }
}

// ---------------- MFMA 3^3 conv: 27 shifted GEMMs (padded LDS) ---------------
// Chunk c = kb*4+kg -> short offset kg*8 (base) + kb*32 (immediate).
template <int CIN, int COUT, int TZ, int TY, int INS, int REDUCE>
__global__ void __launch_bounds__(512) convmf_k(
    const bf16* __restrict__ act, const bf16* __restrict__ wpk,
    bf16* __restrict__ out, double* __restrict__ pbuf, int D, int H, int W) {
  constexpr int CH = CIN / 8;
  constexpr int RBS = CIN + 8;         // padded row stride (shorts)
  constexpr int HZ = TZ + 2, HY = TY + 2;
  constexpr int HALO = HZ * HY * 18;
  constexpr int MS = TZ * TY / 4;
  constexpr int NS = COUT / 32;
  constexpr int NWT = COUT / 16;
  constexpr int KB = CIN / 32;
  __shared__ short lds[HALO * RBS];
  __shared__ float2 red[8][NS][16];
  const int t = threadIdx.x;
  const int gx0 = blockIdx.x * 16, gy0 = blockIdx.y * TY, gz0 = blockIdx.z * TZ;
  const short* actS = (const short*)act;
  for (int cid = t; cid < HALO * CH; cid += 512) {
    int pos = cid / CH, c = cid - pos * CH;
    int hx = pos % 18; int r = pos / 18; int hy = r % HY; int hz = r / HY;
    int gz = gz0 + hz - 1, gy = gy0 + hy - 1, gx = gx0 + hx - 1;
    uint4 v = {0u, 0u, 0u, 0u};
    if (((unsigned)gz < (unsigned)D) & ((unsigned)gy < (unsigned)H) & ((unsigned)gx < (unsigned)W)) {
      size_t vox = (size_t)(gz * H + gy) * W + gx;
      if (INS == 8) { if (c == 0) v = *(const uint4*)(actS + vox * 8); }
      else v = *(const uint4*)(actS + vox * CIN + c * 8);
    }
    *(uint4*)(lds + pos * RBS + c * 8) = v;
  }
  __syncthreads();
  const int lane = t & 63, wid = t >> 6;
  const int mw = wid & 3, nw = wid >> 2;
  const int lid = lane & 15, kg = lane >> 4;
  f32x4 acc[MS][NS];
#pragma unroll
  for (int ms = 0; ms < MS; ++ms)
#pragma unroll
    for (int n = 0; n < NS; ++n) acc[ms][n] = {0.f, 0.f, 0.f, 0.f};
  int rowbase[MS];                     // LDS short-offset base per M-subtile
#pragma unroll
  for (int ms = 0; ms < MS; ++ms) {
    int r = mw * MS + ms;
    rowbase[ms] = (((r / TY) * HY + (r % TY)) * 18 + lid) * RBS + kg * 8;
  }
  const short* wp = (const short*)wpk;
#pragma unroll 1
  for (int kz = 0; kz < 3; ++kz)
#pragma unroll 1
    for (int ky = 0; ky < 3; ++ky) {
      const int dbase = ((kz * HY + ky) * 18) * RBS;
#pragma unroll
      for (int kx = 0; kx < 3; ++kx) {
        const int off = (kz * 3 + ky) * 3 + kx;
        short8 bq[NS][KB];
#pragma unroll
        for (int n = 0; n < NS; ++n)
#pragma unroll
          for (int kb = 0; kb < KB; ++kb)
            bq[n][kb] = *(const short8*)(wp + ((((size_t)off * NWT + nw * NS + n) * KB + kb) << 9) + lane * 8);
#pragma unroll
        for (int ms = 0; ms < MS; ++ms) {
#pragma unroll
          for (int kb = 0; kb < KB; ++kb) {
            short8 a = *(const short8*)(lds + rowbase[ms] + dbase + kx * RBS + kb * 32);
#pragma unroll
            for (int n = 0; n < NS; ++n)
              acc[ms][n] = __builtin_amdgcn_mfma_f32_16x16x32_bf16(a, bq[n][kb], acc[ms][n], 0, 0, 0);
          }
        }
      }
    }
  const int xe = kg * 4;
#pragma unroll
  for (int ms = 0; ms < MS; ++ms) {
    int r = mw * MS + ms;
    int z = gz0 + r / TY, y = gy0 + r % TY;
    size_t voxb = (size_t)(z * H + y) * W + gx0;
#pragma unroll
    for (int n = 0; n < NS; ++n) {
      int co = nw * NS * 16 + n * 16 + lid;
#pragma unroll
      for (int rg = 0; rg < 4; ++rg)
        out[(voxb + xe + rg) * COUT + co] = __float2bfloat16(acc[ms][n][rg]);
    }
  }
  if (REDUCE) {
#pragma unroll
    for (int n = 0; n < NS; ++n) {
      float s = 0.f, q = 0.f;
#pragma unroll
      for (int ms = 0; ms < MS; ++ms)
#pragma unroll
        for (int rg = 0; rg < 4; ++rg) {
          float v = acc[ms][n][rg];
          s += v; q += v * v;
        }
      s += __shfl_xor(s, 16); q += __shfl_xor(q, 16);
      s += __shfl_xor(s, 32); q += __shfl_xor(q, 32);
      if (lane < 16) red[wid][n][lane] = make_float2(s, q);
    }
    __syncthreads();
    if (t < COUT) {
      const int nw_ = t / (NS * 16);
      const int rem = t - nw_ * NS * 16;
      const int n_ = rem >> 4, lid_ = rem & 15;
      float S = 0.f, Q = 0.f;
#pragma unroll
      for (int m = 0; m < 4; ++m) {
        float2 v = red[nw_ * 4 + m][n_][lid_];
        S += v.x; Q += v.y;
      }
      const int G = gridDim.x * gridDim.y * gridDim.z;
      const int bid = blockIdx.x + gridDim.x * (blockIdx.y + gridDim.y * blockIdx.z);
      pbuf[((size_t)t * G + bid) * 2 + 0] = (double)S;
      pbuf[((size_t)t * G + bid) * 2 + 1] = (double)Q;
    }
  }
}

// ---------------- conv4 MFMA 16x16x32 (padded LDS): bufA -> vf f32 [3][N] ----
template <int TZ, int TY>
__global__ void __launch_bounds__(512) conv4mf_k(
    const bf16* __restrict__ act, const bf16* __restrict__ wpk,
    const float* __restrict__ bias, float* __restrict__ vf, int D, int H, int W) {
  constexpr int CH = 4;
  constexpr int RBS = 40;              // 32 + 8 padded row stride
  constexpr int HZ = TZ + 2, HY = TY + 2;
  constexpr int HALO = HZ * HY * 18;
  constexpr int MS = TZ * TY / 8;
  __shared__ short lds[HALO * RBS];
  const int t = threadIdx.x;
  const int gx0 = blockIdx.x * 16, gy0 = blockIdx.y * TY, gz0 = blockIdx.z * TZ;
  const int N = D * H * W;
  const short* actS = (const short*)act;
  for (int cid = t; cid < HALO * CH; cid += 512) {
    int pos = cid / CH, c = cid - pos * CH;
    int hx = pos % 18; int r = pos / 18; int hy = r % HY; int hz = r / HY;
    int gz = gz0 + hz - 1, gy = gy0 + hy - 1, gx = gx0 + hx - 1;
    uint4 v = {0u, 0u, 0u, 0u};
    if (((unsigned)gz < (unsigned)D) & ((unsigned)gy < (unsigned)H) & ((unsigned)gx < (unsigned)W))
      v = *(const uint4*)(actS + ((size_t)(gz * H + gy) * W + gx) * 32 + c * 8);
    *(uint4*)(lds + pos * RBS + c * 8) = v;
  }
  __syncthreads();
  const int lane = t & 63, wid = t >> 6;
  const int lid = lane & 15, kg = lane >> 4;
  f32x4 acc[MS];
#pragma unroll
  for (int ms = 0; ms < MS; ++ms) acc[ms] = {0.f, 0.f, 0.f, 0.f};
  int rowbase[MS];
#pragma unroll
  for (int ms = 0; ms < MS; ++ms) {
    int r = wid * MS + ms;
    rowbase[ms] = (((r / TY) * HY + (r % TY)) * 18 + lid) * RBS + kg * 8;
  }
  const short* wp = (const short*)wpk;
#pragma unroll 1
  for (int kz = 0; kz < 3; ++kz)
#pragma unroll 1
    for (int ky = 0; ky < 3; ++ky) {
      const int dbase = ((kz * HY + ky) * 18) * RBS;
#pragma unroll
      for (int kx = 0; kx < 3; ++kx) {
        const int off = (kz * 3 + ky) * 3 + kx;
        short8 b = *(const short8*)(wp + ((size_t)off << 9) + lane * 8);
#pragma unroll
        for (int ms = 0; ms < MS; ++ms) {
          short8 a = *(const short8*)(lds + rowbase[ms] + dbase + kx * RBS);
          acc[ms] = __builtin_amdgcn_mfma_f32_16x16x32_bf16(a, b, acc[ms], 0, 0, 0);
        }
      }
    }
  if (lid < 3) {
    float bs = bias[lid];
#pragma unroll
    for (int ms = 0; ms < MS; ++ms) {
      int r = wid * MS + ms;
      int z = gz0 + r / TY, y = gy0 + r % TY;
      size_t voxb = (size_t)(z * H + y) * W + gx0 + kg * 4;
      float* p = vf + (size_t)lid * N + voxb;
#pragma unroll
      for (int rg = 0; rg < 4; ++rg) p[rg] += acc[ms][rg] + bs;
    }
  }
}

// ---------------- InstanceNorm stage-2 (musc = mean, inv-std) ----------------
__global__ void stage2_k(const double* __restrict__ pbuf, float2* __restrict__ musc,
                         int N, int G) {
  const int c = blockIdx.x;
  double S = 0, Q = 0;
  for (int g = threadIdx.x; g < G; g += 256) {
    S += pbuf[((size_t)c * G + g) * 2 + 0];
    Q += pbuf[((size_t)c * G + g) * 2 + 1];
  }
  for (int off = 32; off > 0; off >>= 1) {
    S += __shfl_down(S, off); Q += __shfl_down(Q, off);
  }
  __shared__ double ls[4], lq[4];
  const int wid = threadIdx.x >> 6, lane = threadIdx.x & 63;
  if (lane == 0) { ls[wid] = S; lq[wid] = Q; }
  __syncthreads();
  if (threadIdx.x == 0) {
    double St = ls[0] + ls[1] + ls[2] + ls[3];
    double Qt = lq[0] + lq[1] + lq[2] + lq[3];
    double m = St / N;
    double var = Qt / N - m * m;
    musc[c] = make_float2((float)m, (float)(1.0 / sqrt(var + 1e-5)));
  }
}

template <int C>
__global__ void inorm_vc_k(bf16* __restrict__ x, const float2* __restrict__ musc, int N) {
  constexpr int CP = C / 2;
  constexpr int VPB = 256 / CP;
  const int cp = threadIdx.x & (CP - 1);
  const int vt = threadIdx.x / CP;
  float2 m0 = musc[2 * cp], m1 = musc[2 * cp + 1];
  unsigned int* p = (unsigned int*)x;
  int v0 = blockIdx.x * (4 * VPB) + vt;
#pragma unroll
  for (int r = 0; r < 4; ++r) {
    int v = v0 + r * VPB;
    size_t idx = (size_t)v * CP + cp;
    unsigned int u = p[idx];
    float a = mishf((bfu(u & 0xffffu) - m0.x) * m0.y);
    float b = mishf((bfu(u >> 16) - m1.x) * m1.y);
    p[idx] = (unsigned int)fbf(a) | ((unsigned int)fbf(b) << 16);
  }
}

// ---------------- fused 3-axis 7-tap Gaussian (zero pad), 8^3 tile -----------
// Bit-identical to 3 sequential passes: OOB-of-volume positions hold 0.
__global__ void __launch_bounds__(256) smooth3_k(
    const float* __restrict__ in, float* __restrict__ outp, int D, int H, int W) {
  __shared__ float a[14 * 14 * 14];
  __shared__ float b[8 * 14 * 14];
  __shared__ float c2[8 * 8 * 14];
  const int t = threadIdx.x;
  const int ztiles = D / 8;
  const int ch = blockIdx.z / ztiles;
  const int zt = blockIdx.z % ztiles;
  const int gx0 = blockIdx.x * 8 - 3, gy0 = blockIdx.y * 8 - 3, gz0 = zt * 8 - 3;
  const size_t Nv = (size_t)D * H * W;
  const float* p = in + (size_t)ch * Nv;
  const float k1 = 0.60653065971263342f, k2 = 0.13533528323661270f, k3 = 0.011108996538242306f;
  const float kn = 1.f / (1.f + 2.f * (k1 + k2 + k3));
  const float g0 = kn, g1 = k1 * kn, g2 = k2 * kn, g3 = k3 * kn;
  for (int cid = t; cid < 14 * 14 * 14; cid += 256) {
    int xx = cid % 14; int r = cid / 14; int yy = r % 14; int zz = r / 14;
    int gz = gz0 + zz, gy = gy0 + yy, gx = gx0 + xx;
    float v = 0.f;
    if (((unsigned)gz < (unsigned)D) & ((unsigned)gy < (unsigned)H) & ((unsigned)gx < (unsigned)W))
      v = p[(size_t)(gz * H + gy) * W + gx];
    a[cid] = v;
  }
  __syncthreads();
  // z pass: b[zz][yy][xx], zz 0..7 (a-index zz+3)
  for (int cid = t; cid < 8 * 14 * 14; cid += 256) {
    int xx = cid % 14; int r = cid / 14; int yy = r % 14; int zz = r / 14;
    int base = ((zz + 3) * 14 + yy) * 14 + xx;
    float s = g0 * a[base];
    s += g1 * a[base - 196]; s += g1 * a[base + 196];
    s += g2 * a[base - 392]; s += g2 * a[base + 392];
    s += g3 * a[base - 588]; s += g3 * a[base + 588];
    b[cid] = s;
  }
  __syncthreads();
  // y pass: c2[zz][yy][xx], yy 0..7 (b-index yy+3)
  for (int cid = t; cid < 8 * 8 * 14; cid += 256) {
    int xx = cid % 14; int r = cid / 14; int yy = r % 8; int zz = r / 8;
    int base = (zz * 14 + yy + 3) * 14 + xx;
    float s = g0 * b[base];
    s += g1 * b[base - 14]; s += g1 * b[base + 14];
    s += g2 * b[base - 28]; s += g2 * b[base + 28];
    s += g3 * b[base - 42]; s += g3 * b[base + 42];
    c2[cid] = s;
  }
  __syncthreads();
  // x pass + write
  float* q = outp + (size_t)ch * Nv;
  for (int cid = t; cid < 8 * 8 * 8; cid += 256) {
    int xx = cid & 7; int r = cid >> 3; int yy = r & 7; int zz = r >> 3;
    int base = (zz * 8 + yy) * 14 + xx + 3;
    float s = g0 * c2[base];
    s += g1 * c2[base - 1]; s += g1 * c2[base + 1];
    s += g2 * c2[base - 2]; s += g2 * c2[base + 2];
    s += g3 * c2[base - 3]; s += g3 * c2[base + 3];
    int gz = gz0 + 3 + zz, gy = gy0 + 3 + yy, gx = gx0 + 3 + xx;
    q[(size_t)(gz * H + gy) * W + gx] = s;
  }
}

// ---------------------------------------------------------------------------
extern "C" void kernel_launch(void* const* d_in, const int* in_sizes, int n_in,
                              void* d_out, int out_size, void* d_ws, size_t ws_size,
                              hipStream_t stream) {
  const float* image  = (const float*)d_in[0];
  const float* moving = (const float*)d_in[2];
  const float* w1 = (const float*)d_in[4];
  const float* w2 = (const float*)d_in[5];
  const float* w3 = (const float*)d_in[6];
  const float* w4 = (const float*)d_in[7];
  const float* b4 = (const float*)d_in[8];
  float* out = (float*)d_out;

  const int D1 = 96; const int N1 = D1 * D1 * D1;
  const int D0 = 48; const int N0 = D0 * D0 * D0;

  // ---- workspace layout (~236 MB) ----
  char* wsp = (char*)d_ws;
  double* pbuf  = (double*)wsp;          wsp += (size_t)64 * 13824 * 2 * 8; // 14.2 MB
  float2* musc  = (float2*)wsp;          wsp += 1024;
  bf16* w1p     = (bf16*)wsp;            wsp += 27 * 2 * 1 * 512 * 2;  // K-packed uses 7*2*512
  bf16* w2p     = (bf16*)wsp;            wsp += 27 * 4 * 1 * 512 * 2;
  bf16* w3p     = (bf16*)wsp;            wsp += 27 * 2 * 2 * 512 * 2;
  bf16* w4p     = (bf16*)wsp;            wsp += 27 * 1 * 1 * 512 * 2;
  float* si0    = (float*)wsp;           wsp += (size_t)N0 * 4;
  float* smov0  = (float*)wsp;           wsp += (size_t)N0 * 4;
  float* vf0    = (float*)wsp;           wsp += 3 * (size_t)N1 * 4;
  float* vf1    = (float*)wsp;           wsp += 3 * (size_t)N1 * 4;
  bf16* feat    = (bf16*)wsp;            wsp += 8 * (size_t)N1 * 2;
  bf16* bufA    = (bf16*)wsp;            wsp += 32 * (size_t)N1 * 2;
  bf16* bufB    = (bf16*)wsp;            wsp += 64 * (size_t)N1 * 2;

  // ---- weight packing (bf16, fragment order; conv1 K-packed) ----
  pack_w1p_k<<<(7 * 2 * 512 + 255) / 256, 256, 0, stream>>>(w1, w1p);
  pack_wf_k<<<(27 * 4 * 512 + 255) / 256, 256, 0, stream>>>(w2, w2p, 4, 1, 64, 32);
  pack_wf_k<<<(27 * 4 * 512 + 255) / 256, 256, 0, stream>>>(w3, w3p, 2, 2, 32, 64);
  pack_wf_k<<<(27 * 1 * 512 + 255) / 256, 256, 0, stream>>>(w4, w4p, 1, 1, 3, 32);

  // ---- level 0 setup ----
  down2x_k<<<N0 / 256, 256, 0, stream>>>(image, si0, D0, D0, D0);
  down2x_k<<<N0 / 256, 256, 0, stream>>>(moving, smov0, D0, D0, D0);
  zero_k<<<3 * N0 / 256, 256, 0, stream>>>(vf0, 3 * N0);

  float* vfc = vf0;
  float* vfa = vf1;

  auto run_level = [&](const float* si, const float* smov, int Dd, float* last_dst) {
    const int N = Dd * Dd * Dd;
    const dim3 gw(Dd / 8, Dd / 8, Dd / 4);    // warpforce tile 8x8x4
    const dim3 g1(Dd / 16, Dd / 4, Dd / 4);   // conv1/conv2/conv4: 16x4x4
    const dim3 g3(Dd / 16, Dd / 4, Dd / 2);   // conv3: 16x4x2
    const dim3 gs(Dd / 8, Dd / 8, (Dd / 8) * 3);  // fused smooth
    const int G1 = g1.x * g1.y * g1.z;
    const int G3 = g3.x * g3.y * g3.z;
    for (int it = 0; it < 2; ++it) {
      warpforce_k<<<gw, 256, 0, stream>>>(smov, vfc, si, feat, Dd, Dd, Dd);

      conv1p_k<4, 4><<<g1, 512, 0, stream>>>(feat, w1p, bufA, pbuf, Dd, Dd, Dd);
      stage2_k<<<32, 256, 0, stream>>>(pbuf, musc, N, G1);
      inorm_vc_k<32><<<N / 64, 256, 0, stream>>>(bufA, musc, N);

      convmf_k<32, 64, 4, 4, 32, 1><<<g1, 512, 0, stream>>>(bufA, w2p, bufB, pbuf, Dd, Dd, Dd);
      stage2_k<<<64, 256, 0, stream>>>(pbuf, musc, N, G1);
      inorm_vc_k<64><<<N / 32, 256, 0, stream>>>(bufB, musc, N);

      convmf_k<64, 32, 2, 4, 64, 1><<<g3, 512, 0, stream>>>(bufB, w3p, bufA, pbuf, Dd, Dd, Dd);
      stage2_k<<<32, 256, 0, stream>>>(pbuf, musc, N, G3);
      inorm_vc_k<32><<<N / 64, 256, 0, stream>>>(bufA, musc, N);

      conv4mf_k<4, 4><<<g1, 512, 0, stream>>>(bufA, w4p, b4, vfc, Dd, Dd, Dd);

      float* dst = (it == 1 && last_dst) ? last_dst : vfa;
      smooth3_k<<<gs, 256, 0, stream>>>(vfc, dst, Dd, Dd, Dd);
      vfa = vfc; vfc = dst;
    }
  };

  // ---- level 0 (48^3) ----
  run_level(si0, smov0, D0, nullptr);

  // ---- upsample vf to 96^3, scale displacements by 2 ----
  up2x_vf_k<<<dim3(N1 / 256, 3), 256, 0, stream>>>(vfc, vfa, D1, D1, D1);
  { float* tmp = vfc; vfc = vfa; vfa = tmp; }

  // ---- level 1 (96^3): final smooth writes vf directly into d_out[+N1] ----
  run_level(image, moving, D1, out + N1);

  // ---- output 0: warped_full from vf (= out+N1) ----
  warp_k<<<N1 / 256, 256, 0, stream>>>(moving, vfc, out, D1, D1, D1);
}